// Round 3
// baseline (505.866 us; speedup 1.0000x reference)
//
#include <hip/hip_runtime.h>
#include <stdint.h>

// DynamicSparseLinearAttention on MI355X.
// N=4, L=8192, H=8, D=V=128. Layout [n][l][h][d], row stride H*D = 1024 floats.
//
// R2 insight: the h-interleaved layout makes any per-(n,h) stream 1/8-dense
// (512B per 4KB) -> ~1.3 TB/s effective. Fix: per-n two-stage phase 1.
//  retile:        contiguous all-h reads, LDS transpose, write bf16
//                 fragment-ready tiles Ktil/Vtil[h][sb][d(128)][s(32)]
//                 (featmap applied to K; Ksum accumulated for free).
//  kv_from_tiles: pure bf16 MFMA GEMM; fragments are single 16B/lane loads
//                 (1KB contiguous per wave instr), no LDS; tiles are L3-hot.
//  attn_out:      unchanged from R1 (out = (Qf@KV)*Z, bf16 MFMA).

#define LSEQ 8192
#define NHD  1024   // H*D

typedef __attribute__((ext_vector_type(4))) float f32x4;
typedef __attribute__((ext_vector_type(8))) short bf16x8;

static __device__ __forceinline__ unsigned short f2bf(float x) {
  union { float f; uint32_t u; } v; v.f = x;
  uint32_t r = v.u + 0x7FFFu + ((v.u >> 16) & 1u);  // RNE
  return (unsigned short)(r >> 16);
}
static __device__ __forceinline__ uint32_t pack_bf(float a, float b) {
  return (uint32_t)f2bf(a) | ((uint32_t)f2bf(b) << 16);
}
static __device__ __forceinline__ float featmap(float x) {
  // elu(x)+1 = x+1 (x>0) else exp(x)
  return x > 0.f ? x + 1.f : __expf(x);
}

// ---------------- Phase 1a: retile one n ----------------
// Grid 256 (sb = 32-row s-tile), 512 threads. Reads 32 full rows (128KB) of K
// then V contiguously; LDS-transposes to bf16 tiles [h][sb][d][32].
// Thread t owns output d-rows 2l,2l+1 of h=w (hd = 2t, 2t+1).
__global__ __launch_bounds__(512) void retile(const float* __restrict__ keys,
                                              const float* __restrict__ values,
                                              unsigned short* __restrict__ ktil,
                                              unsigned short* __restrict__ vtil,
                                              float* __restrict__ ksumg,
                                              int n) {
  __shared__ uint32_t lds[16384];   // 32 s-rows x 512 dwords (1024 bf16)
  const int tid = threadIdx.x;
  const int sbg = blockIdx.x;       // 0..255
  const int w = tid >> 6, l = tid & 63;
  const size_t gbase = ((size_t)n * LSEQ + (size_t)sbg * 32) * NHD;

  // ---- K pass (featmap + Ksum) ----
#pragma unroll
  for (int it = 0; it < 16; ++it) {
    int idx4 = it * 512 + tid;
    float4 q = *(const float4*)(keys + gbase + (size_t)idx4 * 4);
    lds[idx4 * 2]     = pack_bf(featmap(q.x), featmap(q.y));
    lds[idx4 * 2 + 1] = pack_bf(featmap(q.z), featmap(q.w));
  }
  __syncthreads();
  {
    uint32_t dw[32];
#pragma unroll
    for (int s = 0; s < 32; ++s) dw[s] = lds[s * 512 + tid];
    float ks0 = 0.f, ks1 = 0.f;
#pragma unroll
    for (int s = 0; s < 32; ++s) {
      ks0 += __uint_as_float(dw[s] << 16);
      ks1 += __uint_as_float(dw[s] & 0xFFFF0000u);
    }
    uint32_t u0[16], u1[16];
#pragma unroll
    for (int q = 0; q < 16; ++q) {
      u0[q] = (dw[2 * q] & 0xFFFFu) | (dw[2 * q + 1] << 16);
      u1[q] = (dw[2 * q] >> 16) | (dw[2 * q + 1] & 0xFFFF0000u);
    }
    size_t ob = (((size_t)w * 256 + sbg) * 128 + 2 * l) * 32;  // bf16 elems
    uint4* p0 = (uint4*)(ktil + ob);
    uint4* p1 = (uint4*)(ktil + ob + 32);
#pragma unroll
    for (int q = 0; q < 4; ++q) {
      p0[q] = make_uint4(u0[4 * q], u0[4 * q + 1], u0[4 * q + 2], u0[4 * q + 3]);
      p1[q] = make_uint4(u1[4 * q], u1[4 * q + 1], u1[4 * q + 2], u1[4 * q + 3]);
    }
    atomicAdd(&ksumg[((size_t)n * 8 + w) * 128 + 2 * l], ks0);
    atomicAdd(&ksumg[((size_t)n * 8 + w) * 128 + 2 * l + 1], ks1);
  }
  __syncthreads();

  // ---- V pass (raw) ----
#pragma unroll
  for (int it = 0; it < 16; ++it) {
    int idx4 = it * 512 + tid;
    float4 q = *(const float4*)(values + gbase + (size_t)idx4 * 4);
    lds[idx4 * 2]     = pack_bf(q.x, q.y);
    lds[idx4 * 2 + 1] = pack_bf(q.z, q.w);
  }
  __syncthreads();
  {
    uint32_t dw[32];
#pragma unroll
    for (int s = 0; s < 32; ++s) dw[s] = lds[s * 512 + tid];
    uint32_t u0[16], u1[16];
#pragma unroll
    for (int q = 0; q < 16; ++q) {
      u0[q] = (dw[2 * q] & 0xFFFFu) | (dw[2 * q + 1] << 16);
      u1[q] = (dw[2 * q] >> 16) | (dw[2 * q + 1] & 0xFFFF0000u);
    }
    size_t ob = (((size_t)w * 256 + sbg) * 128 + 2 * l) * 32;
    uint4* p0 = (uint4*)(vtil + ob);
    uint4* p1 = (uint4*)(vtil + ob + 32);
#pragma unroll
    for (int q = 0; q < 4; ++q) {
      p0[q] = make_uint4(u0[4 * q], u0[4 * q + 1], u0[4 * q + 2], u0[4 * q + 3]);
      p1[q] = make_uint4(u1[4 * q], u1[4 * q + 1], u1[4 * q + 2], u1[4 * q + 3]);
    }
  }
}

// ---------------- Phase 1b: KV GEMM from tiles (one n) ----------------
// Grid (32 chunks, 8 h), 512 threads = 8 waves = 2 (d) x 4 (v).
// Fragments: lane reads 16B contiguous; wave instr = 1KB contiguous.
__global__ __launch_bounds__(512) void kv_from_tiles(const unsigned short* __restrict__ ktil,
                                                     const unsigned short* __restrict__ vtil,
                                                     float* __restrict__ kvt,
                                                     int n) {
  const int tid = threadIdx.x;
  const int c = blockIdx.x;    // 0..31 : 8 sb (256 s) each
  const int h = blockIdx.y;    // 0..7
  const int lane = tid & 63, w = tid >> 6;
  const int wr = w >> 2, wc = w & 3;
  const int lr = lane & 15, lg = lane >> 4;

  f32x4 acc[4][2] = {};
  const unsigned short* ka = ktil + (((size_t)h * 256 + c * 8) * 128) * 32 + lg * 8;
  const unsigned short* va = vtil + (((size_t)h * 256 + c * 8) * 128) * 32 + lg * 8;

  for (int sb = 0; sb < 8; ++sb) {
    bf16x8 af[4], bfr[2];
#pragma unroll
    for (int fr = 0; fr < 4; ++fr)
      af[fr] = *(const bf16x8*)(ka + ((size_t)sb * 128 + wr * 64 + fr * 16 + lr) * 32);
#pragma unroll
    for (int fc = 0; fc < 2; ++fc)
      bfr[fc] = *(const bf16x8*)(va + ((size_t)sb * 128 + wc * 32 + fc * 16 + lr) * 32);
#pragma unroll
    for (int fr = 0; fr < 4; ++fr)
#pragma unroll
      for (int fc = 0; fc < 2; ++fc)
        acc[fr][fc] = __builtin_amdgcn_mfma_f32_16x16x32_bf16(af[fr], bfr[fc], acc[fr][fc], 0, 0, 0);
  }

  // C/D layout: col(v)=lane&15, row(d)=(lane>>4)*4+j. Store KVT[v][d].
  float* dst = kvt + ((size_t)n * 8 + h) * 16384;
#pragma unroll
  for (int fr = 0; fr < 4; ++fr)
#pragma unroll
    for (int fc = 0; fc < 2; ++fc)
#pragma unroll
      for (int j = 0; j < 4; ++j) {
        int d = wr * 64 + fr * 16 + lg * 4 + j;
        int v = wc * 32 + fc * 16 + lr;
        atomicAdd(&dst[v * 128 + d], acc[fr][fc][j]);
      }
}

// ---------------- Phase 2 (unchanged) ----------------
__global__ __launch_bounds__(256) void attn_out(const float* __restrict__ queries,
                                                const float* __restrict__ kvt,
                                                const float* __restrict__ ksumg,
                                                const float* __restrict__ thrp,
                                                float* __restrict__ out) {
  const int tid = threadIdx.x;
  const int mc = blockIdx.x;   // 0..63 : 128-row tile
  const int nh = blockIdx.y;   // 0..31
  const int n = nh >> 3, h = nh & 7;
  const int l0 = mc * 128;
  const size_t qoff = ((size_t)n * LSEQ + l0) * NHD + (size_t)h * 128;

  __shared__ __align__(16) uint32_t As[128 * 64];
  __shared__ __align__(16) uint32_t Bs[128 * 64];
  __shared__ float ksum_s[128];
  __shared__ float spart[128];
  __shared__ float zrow[128];

  if (tid < 128) ksum_s[tid] = ksumg[nh * 128 + tid];

  const float* kvp = kvt + (size_t)nh * 16384;
#pragma unroll
  for (int it = 0; it < 16; ++it) {
    int fi = it * 256 + tid;
    int rr = fi >> 5, c4 = fi & 31;
    float4 q = *(const float4*)(queries + qoff + (size_t)rr * NHD + c4 * 4);
    uint32_t p01 = pack_bf(featmap(q.x), featmap(q.y));
    uint32_t p23 = pack_bf(featmap(q.z), featmap(q.w));
    int ch = rr * 16 + ((c4 >> 1) ^ (rr & 7));
    As[ch * 4 + (c4 & 1) * 2]     = p01;
    As[ch * 4 + (c4 & 1) * 2 + 1] = p23;
  }
#pragma unroll
  for (int it = 0; it < 16; ++it) {
    int fi = it * 256 + tid;
    int rr = fi >> 5, c4 = fi & 31;
    float4 q = *(const float4*)(kvp + fi * 4);
    uint32_t p01 = pack_bf(q.x, q.y);
    uint32_t p23 = pack_bf(q.z, q.w);
    int ch = rr * 16 + ((c4 >> 1) ^ (rr & 7));
    Bs[ch * 4 + (c4 & 1) * 2]     = p01;
    Bs[ch * 4 + (c4 & 1) * 2 + 1] = p23;
  }
  __syncthreads();

  {
    int rr = tid & 127, half = tid >> 7;
    float sum = 0.f;
#pragma unroll
    for (int cc = 0; cc < 8; ++cc) {
      int c8 = half * 8 + cc;
      uint4 raw = *(const uint4*)&As[(rr * 16 + (c8 ^ (rr & 7))) * 4];
      const float* kk = &ksum_s[c8 * 8];
      sum += __uint_as_float(raw.x << 16) * kk[0];
      sum += __uint_as_float(raw.x & 0xFFFF0000u) * kk[1];
      sum += __uint_as_float(raw.y << 16) * kk[2];
      sum += __uint_as_float(raw.y & 0xFFFF0000u) * kk[3];
      sum += __uint_as_float(raw.z << 16) * kk[4];
      sum += __uint_as_float(raw.z & 0xFFFF0000u) * kk[5];
      sum += __uint_as_float(raw.w << 16) * kk[6];
      sum += __uint_as_float(raw.w & 0xFFFF0000u) * kk[7];
    }
    if (half) spart[rr] = sum;
    __syncthreads();
    if (!half) {
      float score = sum + spart[rr];
      float thr = thrp[0];
      float sp = score > thr ? score : 0.f;
      zrow[rr] = 1.f / (sp + 1e-6f);
    }
    __syncthreads();
  }

  const int lane = tid & 63;
  const int w = tid >> 6;
  const int lr = lane & 15, lg = lane >> 4;
  f32x4 acc0[8] = {};
  f32x4 acc1[8] = {};
#pragma unroll
  for (int ks = 0; ks < 4; ++ks) {
    int c8 = ks * 4 + lg;
    int cs = c8 ^ (lr & 7);
    int r0 = w * 32 + lr;
    bf16x8 a0 = *(const bf16x8*)&As[(r0 * 16 + cs) * 4];
    bf16x8 a1 = *(const bf16x8*)&As[((r0 + 16) * 16 + cs) * 4];
#pragma unroll
    for (int ct = 0; ct < 8; ++ct) {
      int v = ct * 16 + lr;
      bf16x8 b = *(const bf16x8*)&Bs[(v * 16 + cs) * 4];
      acc0[ct] = __builtin_amdgcn_mfma_f32_16x16x32_bf16(a0, b, acc0[ct], 0, 0, 0);
      acc1[ct] = __builtin_amdgcn_mfma_f32_16x16x32_bf16(a1, b, acc1[ct], 0, 0, 0);
    }
  }

  float z0[4], z1[4];
#pragma unroll
  for (int j = 0; j < 4; ++j) {
    z0[j] = zrow[w * 32 + lg * 4 + j];
    z1[j] = zrow[w * 32 + 16 + lg * 4 + j];
  }
  float* op = out + qoff;
#pragma unroll
  for (int ct = 0; ct < 8; ++ct)
#pragma unroll
    for (int j = 0; j < 4; ++j) {
      int row = w * 32 + lg * 4 + j;
      op[(size_t)row * NHD + ct * 16 + lr]        = acc0[ct][j] * z0[j];
      op[(size_t)(row + 16) * NHD + ct * 16 + lr] = acc1[ct][j] * z1[j];
    }
}

extern "C" void kernel_launch(void* const* d_in, const int* in_sizes, int n_in,
                              void* d_out, int out_size, void* d_ws, size_t ws_size,
                              hipStream_t stream) {
  const float* queries  = (const float*)d_in[0];
  const float* keys     = (const float*)d_in[1];
  const float* values   = (const float*)d_in[2];
  const float* threshold = (const float*)d_in[3];
  float* out = (float*)d_out;

  // ws layout: kvt (2MB) | ksumg (16KB) | ktil (16.78MB bf16) | vtil (16.78MB)
  float* kvt   = (float*)d_ws;
  float* ksumg = kvt + 32 * 16384;
  unsigned short* ktil = (unsigned short*)(ksumg + 32 * 128);
  unsigned short* vtil = ktil + (size_t)8 * 256 * 128 * 32;

  hipMemsetAsync(d_ws, 0, (size_t)(32 * 16384 + 32 * 128) * sizeof(float), stream);
  for (int n = 0; n < 4; ++n) {
    retile<<<256, 512, 0, stream>>>(keys, values, ktil, vtil, ksumg, n);
    kv_from_tiles<<<dim3(32, 8), 512, 0, stream>>>(ktil, vtil, kvt, n);
  }
  attn_out<<<dim3(64, 32), 256, 0, stream>>>(queries, kvt, ksumg, threshold, out);
}

// Round 4
// 456.197 us; speedup vs baseline: 1.1089x; 1.1089x over previous
//
#include <hip/hip_runtime.h>
#include <stdint.h>

// DynamicSparseLinearAttention on MI355X.
// N=4, L=8192, H=8, D=V=128. Layout [n][l][h][d], row stride H*D = 1024 floats.
//
// Pipeline (5 launches, stream-ordered):
//  zero_ws:       zero kvt+ksumg (own kernel: rocclr fill measured 27 GB/s!).
//  retile:        all-n grid. Contiguous all-h reads, LDS transpose, write bf16
//                 fragment-ready tiles [slot][h][sb][d(128)][s(32)] + Ksum atomics.
//  kv_from_tiles: all-n grid. Pure bf16 MFMA GEMM from tiles (16B/lane frag
//                 loads, 1KB/wave instr, L3-hot), fp32 atomics into kvt[nh][v][d].
//  attn_out:      NO LDS / NO barriers. Contraction dim (d) is memory-contiguous
//                 for both Q and KVT, so A/B fragments load directly to regs
//                 (featmap+cvt in VALU, hidden under BW); score via in-reg dot +
//                 shfl_xor; Z redistributed via shfl. Target: Q+out BW floor.

#define LSEQ 8192
#define NHD  1024   // H*D

typedef __attribute__((ext_vector_type(4))) float f32x4;
typedef __attribute__((ext_vector_type(8))) short bf16x8;

static __device__ __forceinline__ unsigned short f2bf(float x) {
  union { float f; uint32_t u; } v; v.f = x;
  uint32_t r = v.u + 0x7FFFu + ((v.u >> 16) & 1u);  // RNE
  return (unsigned short)(r >> 16);
}
static __device__ __forceinline__ uint32_t pack_bf(float a, float b) {
  return (uint32_t)f2bf(a) | ((uint32_t)f2bf(b) << 16);
}
static __device__ __forceinline__ float featmap(float x) {
  // elu(x)+1 = x+1 (x>0) else exp(x)
  return x > 0.f ? x + 1.f : __expf(x);
}

// ---------------- zero workspace ----------------
__global__ void zero_ws(float4* p, int n4) {
  int id = blockIdx.x * 256 + threadIdx.x;
  if (id < n4) p[id] = make_float4(0.f, 0.f, 0.f, 0.f);
}

// ---------------- Phase 1a: retile ----------------
// Grid (256 sb, NL), 512 threads. Reads 32 full rows (128KB) of K then V
// contiguously; LDS-transposes to bf16 tiles [slot][h][sb][d][32].
__global__ __launch_bounds__(512) void retile(const float* __restrict__ keys,
                                              const float* __restrict__ values,
                                              unsigned short* __restrict__ ktil,
                                              unsigned short* __restrict__ vtil,
                                              float* __restrict__ ksumg,
                                              int nbase) {
  __shared__ uint32_t lds[16384];   // 32 s-rows x 512 dwords (1024 bf16)
  const int tid = threadIdx.x;
  const int sbg = blockIdx.x;       // 0..255
  const int slot = blockIdx.y;
  const int n = nbase + slot;
  const int w = tid >> 6, l = tid & 63;   // w = h, l -> d rows 2l, 2l+1
  const size_t gbase = ((size_t)n * LSEQ + (size_t)sbg * 32) * NHD;

  // ---- K pass (featmap + Ksum) ----
#pragma unroll
  for (int it = 0; it < 16; ++it) {
    int idx4 = it * 512 + tid;
    float4 q = *(const float4*)(keys + gbase + (size_t)idx4 * 4);
    lds[idx4 * 2]     = pack_bf(featmap(q.x), featmap(q.y));
    lds[idx4 * 2 + 1] = pack_bf(featmap(q.z), featmap(q.w));
  }
  __syncthreads();
  {
    uint32_t dw[32];
#pragma unroll
    for (int s = 0; s < 32; ++s) dw[s] = lds[s * 512 + tid];
    float ks0 = 0.f, ks1 = 0.f;
#pragma unroll
    for (int s = 0; s < 32; ++s) {
      ks0 += __uint_as_float(dw[s] << 16);
      ks1 += __uint_as_float(dw[s] & 0xFFFF0000u);
    }
    uint32_t u0[16], u1[16];
#pragma unroll
    for (int q = 0; q < 16; ++q) {
      u0[q] = (dw[2 * q] & 0xFFFFu) | (dw[2 * q + 1] << 16);
      u1[q] = (dw[2 * q] >> 16) | (dw[2 * q + 1] & 0xFFFF0000u);
    }
    size_t ob = ((((size_t)slot * 8 + w) * 256 + sbg) * 128 + 2 * l) * 32;
    uint4* p0 = (uint4*)(ktil + ob);
    uint4* p1 = (uint4*)(ktil + ob + 32);
#pragma unroll
    for (int q = 0; q < 4; ++q) {
      p0[q] = make_uint4(u0[4 * q], u0[4 * q + 1], u0[4 * q + 2], u0[4 * q + 3]);
      p1[q] = make_uint4(u1[4 * q], u1[4 * q + 1], u1[4 * q + 2], u1[4 * q + 3]);
    }
    atomicAdd(&ksumg[((size_t)n * 8 + w) * 128 + 2 * l], ks0);
    atomicAdd(&ksumg[((size_t)n * 8 + w) * 128 + 2 * l + 1], ks1);
  }
  __syncthreads();

  // ---- V pass (raw) ----
#pragma unroll
  for (int it = 0; it < 16; ++it) {
    int idx4 = it * 512 + tid;
    float4 q = *(const float4*)(values + gbase + (size_t)idx4 * 4);
    lds[idx4 * 2]     = pack_bf(q.x, q.y);
    lds[idx4 * 2 + 1] = pack_bf(q.z, q.w);
  }
  __syncthreads();
  {
    uint32_t dw[32];
#pragma unroll
    for (int s = 0; s < 32; ++s) dw[s] = lds[s * 512 + tid];
    uint32_t u0[16], u1[16];
#pragma unroll
    for (int q = 0; q < 16; ++q) {
      u0[q] = (dw[2 * q] & 0xFFFFu) | (dw[2 * q + 1] << 16);
      u1[q] = (dw[2 * q] >> 16) | (dw[2 * q + 1] & 0xFFFF0000u);
    }
    size_t ob = ((((size_t)slot * 8 + w) * 256 + sbg) * 128 + 2 * l) * 32;
    uint4* p0 = (uint4*)(vtil + ob);
    uint4* p1 = (uint4*)(vtil + ob + 32);
#pragma unroll
    for (int q = 0; q < 4; ++q) {
      p0[q] = make_uint4(u0[4 * q], u0[4 * q + 1], u0[4 * q + 2], u0[4 * q + 3]);
      p1[q] = make_uint4(u1[4 * q], u1[4 * q + 1], u1[4 * q + 2], u1[4 * q + 3]);
    }
  }
}

// ---------------- Phase 1b: KV GEMM from tiles ----------------
// Grid (32 c, 8 h, NL), 512 threads = 8 waves = 2 (d) x 4 (v).
__global__ __launch_bounds__(512) void kv_from_tiles(const unsigned short* __restrict__ ktil,
                                                     const unsigned short* __restrict__ vtil,
                                                     float* __restrict__ kvt,
                                                     int nbase) {
  const int tid = threadIdx.x;
  const int c = blockIdx.x;    // 0..31 : 8 sb (256 s) each
  const int h = blockIdx.y;    // 0..7
  const int slot = blockIdx.z;
  const int n = nbase + slot;
  const int lane = tid & 63, w = tid >> 6;
  const int wr = w >> 2, wc = w & 3;
  const int lr = lane & 15, lg = lane >> 4;

  f32x4 acc[4][2] = {};
  const size_t tbase = ((((size_t)slot * 8 + h) * 256 + c * 8) * 128) * 32 + lg * 8;
  const unsigned short* ka = ktil + tbase;
  const unsigned short* va = vtil + tbase;

  for (int sb = 0; sb < 8; ++sb) {
    bf16x8 af[4], bfr[2];
#pragma unroll
    for (int fr = 0; fr < 4; ++fr)
      af[fr] = *(const bf16x8*)(ka + ((size_t)sb * 128 + wr * 64 + fr * 16 + lr) * 32);
#pragma unroll
    for (int fc = 0; fc < 2; ++fc)
      bfr[fc] = *(const bf16x8*)(va + ((size_t)sb * 128 + wc * 32 + fc * 16 + lr) * 32);
#pragma unroll
    for (int fr = 0; fr < 4; ++fr)
#pragma unroll
      for (int fc = 0; fc < 2; ++fc)
        acc[fr][fc] = __builtin_amdgcn_mfma_f32_16x16x32_bf16(af[fr], bfr[fc], acc[fr][fc], 0, 0, 0);
  }

  // C/D: col(v)=lane&15, row(d)=(lane>>4)*4+j. Accumulate into KVT[nh][v][d].
  float* dst = kvt + ((size_t)n * 8 + h) * 16384;
#pragma unroll
  for (int fr = 0; fr < 4; ++fr)
#pragma unroll
    for (int fc = 0; fc < 2; ++fc)
#pragma unroll
      for (int j = 0; j < 4; ++j) {
        int d = wr * 64 + fr * 16 + lg * 4 + j;
        int v = wc * 32 + fc * 16 + lr;
        atomicAdd(&dst[v * 128 + d], acc[fr][fc][j]);
      }
}

// ---------------- Phase 2: no-LDS register-direct ----------------
// Grid (64 mc, 32 nh), 256 thr = 4 waves; wave w owns rows mc*128+w*32..+32.
// A-frag: Q rows (contraction d contiguous, featmap+cvt in regs).
// B-frag: KVT[v][d] fp32 from L2 (d contiguous), cvt in regs.
// score: in-reg dot with Ksum + shfl_xor(16,32); Z redistributed via shfl.
__global__ __launch_bounds__(256, 4) void attn_out(const float* __restrict__ q,
                                                   const float* __restrict__ kvt,
                                                   const float* __restrict__ ksumg,
                                                   const float* __restrict__ thrp,
                                                   float* __restrict__ out) {
  const int tid = threadIdx.x;
  const int mc = blockIdx.x, nh = blockIdx.y;
  const int n = nh >> 3, h = nh & 7;
  const int lane = tid & 63, w = tid >> 6;
  const int lr = lane & 15, lg = lane >> 4;
  const int r0 = mc * 128 + w * 32;

  const float* qp0 = q + ((size_t)(n * LSEQ + r0 + lr)) * NHD + h * 128;
  const float* qp1 = qp0 + (size_t)16 * NHD;
  const float* ksp = ksumg + nh * 128 + lg * 8;
  const float* kvp = kvt + (size_t)nh * 16384;  // [v][d]

  f32x4 acc0[8] = {};
  f32x4 acc1[8] = {};
  float dot0 = 0.f, dot1 = 0.f;

#pragma unroll
  for (int ks = 0; ks < 4; ++ks) {
    const int dof = ks * 32 + lg * 8;
    float4 ka = *(const float4*)(ksp + ks * 32);
    float4 kb = *(const float4*)(ksp + ks * 32 + 4);

    float4 qa = *(const float4*)(qp0 + dof);
    float4 qb = *(const float4*)(qp0 + dof + 4);
    float f0 = featmap(qa.x), f1 = featmap(qa.y), f2 = featmap(qa.z), f3 = featmap(qa.w);
    float f4 = featmap(qb.x), f5 = featmap(qb.y), f6 = featmap(qb.z), f7 = featmap(qb.w);
    dot0 += f0 * ka.x + f1 * ka.y + f2 * ka.z + f3 * ka.w
          + f4 * kb.x + f5 * kb.y + f6 * kb.z + f7 * kb.w;
    bf16x8 a0;
    { uint32_t* u = (uint32_t*)&a0;
      u[0] = pack_bf(f0, f1); u[1] = pack_bf(f2, f3);
      u[2] = pack_bf(f4, f5); u[3] = pack_bf(f6, f7); }

    qa = *(const float4*)(qp1 + dof);
    qb = *(const float4*)(qp1 + dof + 4);
    f0 = featmap(qa.x); f1 = featmap(qa.y); f2 = featmap(qa.z); f3 = featmap(qa.w);
    f4 = featmap(qb.x); f5 = featmap(qb.y); f6 = featmap(qb.z); f7 = featmap(qb.w);
    dot1 += f0 * ka.x + f1 * ka.y + f2 * ka.z + f3 * ka.w
          + f4 * kb.x + f5 * kb.y + f6 * kb.z + f7 * kb.w;
    bf16x8 a1;
    { uint32_t* u = (uint32_t*)&a1;
      u[0] = pack_bf(f0, f1); u[1] = pack_bf(f2, f3);
      u[2] = pack_bf(f4, f5); u[3] = pack_bf(f6, f7); }

#pragma unroll
    for (int ct = 0; ct < 8; ++ct) {
      const float* bp = kvp + (ct * 16 + lr) * 128 + dof;
      float4 b0 = *(const float4*)(bp);
      float4 b1 = *(const float4*)(bp + 4);
      bf16x8 bb;
      { uint32_t* u = (uint32_t*)&bb;
        u[0] = pack_bf(b0.x, b0.y); u[1] = pack_bf(b0.z, b0.w);
        u[2] = pack_bf(b1.x, b1.y); u[3] = pack_bf(b1.z, b1.w); }
      acc0[ct] = __builtin_amdgcn_mfma_f32_16x16x32_bf16(a0, bb, acc0[ct], 0, 0, 0);
      acc1[ct] = __builtin_amdgcn_mfma_f32_16x16x32_bf16(a1, bb, acc1[ct], 0, 0, 0);
    }
  }

  dot0 += __shfl_xor(dot0, 16); dot0 += __shfl_xor(dot0, 32);
  dot1 += __shfl_xor(dot1, 16); dot1 += __shfl_xor(dot1, 32);
  const float thr = thrp[0];
  float s0 = dot0 > thr ? dot0 : 0.f;
  float s1 = dot1 > thr ? dot1 : 0.f;
  const float z0 = 1.f / (s0 + 1e-6f);
  const float z1 = 1.f / (s1 + 1e-6f);

  float* op = out + ((size_t)(n * LSEQ + r0)) * NHD + h * 128;
#pragma unroll
  for (int jj = 0; jj < 4; ++jj) {
    int row = lg * 4 + jj;                 // C/D: col=lane&15, row=(lane>>4)*4+jj
    float zz0 = __shfl(z0, row);           // lanes 0..15 hold rows 0..15
    float zz1 = __shfl(z1, row);
#pragma unroll
    for (int ct = 0; ct < 8; ++ct) {
      op[(size_t)row * NHD + ct * 16 + lr]        = acc0[ct][jj] * zz0;
      op[(size_t)(row + 16) * NHD + ct * 16 + lr] = acc1[ct][jj] * zz1;
    }
  }
}

extern "C" void kernel_launch(void* const* d_in, const int* in_sizes, int n_in,
                              void* d_out, int out_size, void* d_ws, size_t ws_size,
                              hipStream_t stream) {
  const float* queries   = (const float*)d_in[0];
  const float* keys      = (const float*)d_in[1];
  const float* values    = (const float*)d_in[2];
  const float* threshold = (const float*)d_in[3];
  float* out = (float*)d_out;

  // ws: kvt (2MB fp32) | ksumg (16KB fp32) | ktil | vtil (bf16 tiles)
  float* kvt   = (float*)d_ws;                 // 32*16384 floats
  float* ksumg = kvt + 32 * 16384;             // 32*128 floats
  unsigned short* ktil = (unsigned short*)(ksumg + 32 * 128);
  const size_t tileN = (size_t)8 * 256 * 128 * 32;      // bf16 elems per n per tensor
  const size_t needAll = (size_t)(32 * 16384 + 32 * 128) * 4 + 2 * 4 * tileN * 2;
  const int NL = (ws_size >= needAll) ? 4 : 1;          // all-n fast path if ws allows
  unsigned short* vtil = ktil + (size_t)NL * tileN;

  zero_ws<<<516, 256, 0, stream>>>((float4*)d_ws, 132096);
  if (NL == 4) {
    retile<<<dim3(256, 4), 512, 0, stream>>>(keys, values, ktil, vtil, ksumg, 0);
    kv_from_tiles<<<dim3(32, 8, 4), 512, 0, stream>>>(ktil, vtil, kvt, 0);
  } else {
    for (int n = 0; n < 4; ++n) {
      retile<<<dim3(256, 1), 512, 0, stream>>>(keys, values, ktil, vtil, ksumg, n);
      kv_from_tiles<<<dim3(32, 8, 1), 512, 0, stream>>>(ktil, vtil, kvt, n);
    }
  }
  attn_out<<<dim3(64, 32), 256, 0, stream>>>(queries, kvt, ksumg, threshold, out);
}

// Round 5
// 387.653 us; speedup vs baseline: 1.3049x; 1.1768x over previous
//
#include <hip/hip_runtime.h>
#include <stdint.h>

// DynamicSparseLinearAttention on MI355X.
// N=4, L=8192, H=8, D=V=128. Layout [n][l][h][d], row stride H*D = 1024 floats.
//
// R4 lesson: device-scope fp32 atomics write through L2 (256MB HBM writes for a
// 2MB buffer) and serialize -> 224us. This version has ZERO atomics, ZERO memset.
//
// 3 launches:
//  retile8:  [n][l][h][d] fp32 -> bf16 tiles [n][h][sb(1024)][d(128)][s(8)].
//            8-row tiles = 32KB LDS = 4 blocks/CU (2x occupancy vs R4).
//            Contiguous row reads, LDS transpose, 32B/thread tile stores.
//            K gets featmap; V raw. No ksum here.
//  kv_heads: per (n,h,v-half) block (64 blocks x 1024 thr) computes full-s
//            KV[d][v] with bf16 MFMA from tiles; fragments are single 16B/lane
//            loads. Ksum via extra MFMA against all-ones B (matrix-pipe free).
//            Writes kvb bf16 [nh][v][d] (fragment-ready) + ksumg. Write-once.
//  attn_out: out[l,v] = (Qf[l,:] @ KV) * Z[l]; Z = 1/(where(s>thr,s,0)+eps);
//            score = Qf.Ksum in-register + shfl_xor. No LDS, no barriers.
//            A-frags: featmap(Q) in regs (d contiguous); B-frags: direct bf16
//            loads from kvb (L2/L3-hot).

#define LSEQ 8192
#define NHD  1024   // H*D

typedef __attribute__((ext_vector_type(4))) float f32x4;
typedef __attribute__((ext_vector_type(8))) short bf16x8;
typedef unsigned short ushort_t;

static __device__ __forceinline__ unsigned short f2bf(float x) {
  union { float f; uint32_t u; } v; v.f = x;
  uint32_t r = v.u + 0x7FFFu + ((v.u >> 16) & 1u);  // RNE
  return (unsigned short)(r >> 16);
}
static __device__ __forceinline__ uint32_t pack_bf(float a, float b) {
  return (uint32_t)f2bf(a) | ((uint32_t)f2bf(b) << 16);
}
static __device__ __forceinline__ float featmap(float x) {
  // elu(x)+1 = x+1 (x>0) else exp(x)
  return x > 0.f ? x + 1.f : __expf(x);
}

// ---------------- Phase 1a: retile (8-row tiles) ----------------
// Grid (1024 sb, 4 n), 512 thr. Block: 8 s-rows x 1024 hd.
// Stage rows contiguously to LDS (f32), transpose-read 2 cols/thread,
// featmap+pack, store 2x16B contiguous per thread.
__global__ __launch_bounds__(512) void retile8(const float* __restrict__ keys,
                                               const float* __restrict__ values,
                                               ushort_t* __restrict__ ktil,
                                               ushort_t* __restrict__ vtil) {
  __shared__ float lds[8 * 1024];
  const int tid = threadIdx.x;
  const int sbg = blockIdx.x;      // 0..1023
  const int n = blockIdx.y;
  const size_t gbase = ((size_t)n * LSEQ + (size_t)sbg * 8) * NHD;
  const int hd0 = 2 * tid;         // this thread's two d-columns
  const size_t ob = ((((size_t)n * 8 + (hd0 >> 7)) * 1024 + sbg) * 128 + (hd0 & 127)) * 8;

  // ---- K ----
  {
    const float4* gp = (const float4*)(keys + gbase);
    float4 r0 = gp[tid], r1 = gp[tid + 512], r2 = gp[tid + 1024], r3 = gp[tid + 1536];
    float4* lp = (float4*)lds;
    lp[tid] = r0; lp[tid + 512] = r1; lp[tid + 1024] = r2; lp[tid + 1536] = r3;
  }
  __syncthreads();
  {
    float2 c[8];
#pragma unroll
    for (int s = 0; s < 8; ++s) c[s] = *(const float2*)&lds[s * 1024 + hd0];
    uint32_t da[4], db[4];
#pragma unroll
    for (int j = 0; j < 4; ++j) {
      da[j] = pack_bf(featmap(c[2 * j].x), featmap(c[2 * j + 1].x));
      db[j] = pack_bf(featmap(c[2 * j].y), featmap(c[2 * j + 1].y));
    }
    *(uint4*)(ktil + ob)     = make_uint4(da[0], da[1], da[2], da[3]);
    *(uint4*)(ktil + ob + 8) = make_uint4(db[0], db[1], db[2], db[3]);
  }
  __syncthreads();

  // ---- V ----
  {
    const float4* gp = (const float4*)(values + gbase);
    float4 r0 = gp[tid], r1 = gp[tid + 512], r2 = gp[tid + 1024], r3 = gp[tid + 1536];
    float4* lp = (float4*)lds;
    lp[tid] = r0; lp[tid + 512] = r1; lp[tid + 1024] = r2; lp[tid + 1536] = r3;
  }
  __syncthreads();
  {
    float2 c[8];
#pragma unroll
    for (int s = 0; s < 8; ++s) c[s] = *(const float2*)&lds[s * 1024 + hd0];
    uint32_t da[4], db[4];
#pragma unroll
    for (int j = 0; j < 4; ++j) {
      da[j] = pack_bf(c[2 * j].x, c[2 * j + 1].x);
      db[j] = pack_bf(c[2 * j].y, c[2 * j + 1].y);
    }
    *(uint4*)(vtil + ob)     = make_uint4(da[0], da[1], da[2], da[3]);
    *(uint4*)(vtil + ob + 8) = make_uint4(db[0], db[1], db[2], db[3]);
  }
}

// ---------------- Phase 1b: per-head full-s KV GEMM ----------------
// Grid (2 vhalf, 8 h, 4 n) = 64 blocks, 1024 thr = 16 waves = 4 wr(d32) x 4 wc(v16).
// No atomics: each block owns a disjoint [d x v-half] slab, written once.
// Ksum = extra MFMA vs all-ones B on wc==0 waves (vh==0 blocks only).
__global__ __launch_bounds__(1024) void kv_heads(const ushort_t* __restrict__ ktil,
                                                 const ushort_t* __restrict__ vtil,
                                                 ushort_t* __restrict__ kvb,
                                                 float* __restrict__ ksumg) {
  const int tid = threadIdx.x;
  const int vh = blockIdx.x;    // 0..1
  const int h = blockIdx.y;     // 0..7
  const int n = blockIdx.z;     // 0..3
  const int nh = n * 8 + h;
  const int lane = tid & 63, w = tid >> 6;
  const int wr = w & 3, wc = w >> 2;     // wr: 32-d slice, wc: 16-v slice of the half
  const int lr = lane & 15, lg = lane >> 4;
  const int vrow = vh * 64 + wc * 16 + lr;

  const ushort_t* ka = ktil + (size_t)nh * 1024 * 1024;   // [sb][d][8] bf16
  const ushort_t* va = vtil + (size_t)nh * 1024 * 1024;

  const ushort_t* kp0 = ka + lg * 1024 + (wr * 32 + lr) * 8;
  const ushort_t* kp1 = kp0 + 16 * 8;
  const ushort_t* vp  = va + lg * 1024 + vrow * 8;

  f32x4 acc0 = {}, acc1 = {};
  f32x4 ak0 = {}, ak1 = {};
  bf16x8 ones;
  { uint32_t* u = (uint32_t*)&ones; u[0] = u[1] = u[2] = u[3] = 0x3F803F80u; }

#pragma unroll 4
  for (int it = 0; it < 256; ++it) {
    bf16x8 b  = *(const bf16x8*)vp;
    bf16x8 a0 = *(const bf16x8*)kp0;
    bf16x8 a1 = *(const bf16x8*)kp1;
    kp0 += 4096; kp1 += 4096; vp += 4096;
    acc0 = __builtin_amdgcn_mfma_f32_16x16x32_bf16(a0, b, acc0, 0, 0, 0);
    acc1 = __builtin_amdgcn_mfma_f32_16x16x32_bf16(a1, b, acc1, 0, 0, 0);
    if (wc == 0 && vh == 0) {
      ak0 = __builtin_amdgcn_mfma_f32_16x16x32_bf16(a0, ones, ak0, 0, 0, 0);
      ak1 = __builtin_amdgcn_mfma_f32_16x16x32_bf16(a1, ones, ak1, 0, 0, 0);
    }
  }

  // D layout: col(v)=lane&15, row(d)=(lane>>4)*4+j. Write kvb[nh][v][d] bf16.
  ushort_t* kd = kvb + (size_t)nh * 16384 + (size_t)vrow * 128;
  {
    int d0 = wr * 32 + lg * 4;
    *(uint2*)(kd + d0)      = make_uint2(pack_bf(acc0[0], acc0[1]), pack_bf(acc0[2], acc0[3]));
    *(uint2*)(kd + d0 + 16) = make_uint2(pack_bf(acc1[0], acc1[1]), pack_bf(acc1[2], acc1[3]));
  }
  if (wc == 0 && vh == 0 && lr == 0) {
    float* ks = ksumg + nh * 128 + wr * 32 + lg * 4;
    *(float4*)(ks)      = make_float4(ak0[0], ak0[1], ak0[2], ak0[3]);
    *(float4*)(ks + 16) = make_float4(ak1[0], ak1[1], ak1[2], ak1[3]);
  }
}

// ---------------- Phase 2: no-LDS register-direct ----------------
// Grid (64 mc, 32 nh), 256 thr = 4 waves; wave w owns rows mc*128+w*32..+32.
__global__ __launch_bounds__(256, 4) void attn_out(const float* __restrict__ q,
                                                   const ushort_t* __restrict__ kvb,
                                                   const float* __restrict__ ksumg,
                                                   const float* __restrict__ thrp,
                                                   float* __restrict__ out) {
  const int tid = threadIdx.x;
  const int mc = blockIdx.x, nh = blockIdx.y;
  const int n = nh >> 3, h = nh & 7;
  const int lane = tid & 63, w = tid >> 6;
  const int lr = lane & 15, lg = lane >> 4;
  const int r0 = mc * 128 + w * 32;

  const float* qp0 = q + ((size_t)(n * LSEQ + r0 + lr)) * NHD + h * 128;
  const float* qp1 = qp0 + (size_t)16 * NHD;
  const float* ksp = ksumg + nh * 128 + lg * 8;
  const ushort_t* kvp = kvb + (size_t)nh * 16384;   // [v][d] bf16

  f32x4 acc0[8] = {};
  f32x4 acc1[8] = {};
  float dot0 = 0.f, dot1 = 0.f;

#pragma unroll
  for (int ks = 0; ks < 4; ++ks) {
    const int dof = ks * 32 + lg * 8;
    float4 ka = *(const float4*)(ksp + ks * 32);
    float4 kb = *(const float4*)(ksp + ks * 32 + 4);

    float4 qa = *(const float4*)(qp0 + dof);
    float4 qb = *(const float4*)(qp0 + dof + 4);
    float f0 = featmap(qa.x), f1 = featmap(qa.y), f2 = featmap(qa.z), f3 = featmap(qa.w);
    float f4 = featmap(qb.x), f5 = featmap(qb.y), f6 = featmap(qb.z), f7 = featmap(qb.w);
    dot0 += f0 * ka.x + f1 * ka.y + f2 * ka.z + f3 * ka.w
          + f4 * kb.x + f5 * kb.y + f6 * kb.z + f7 * kb.w;
    bf16x8 a0;
    { uint32_t* u = (uint32_t*)&a0;
      u[0] = pack_bf(f0, f1); u[1] = pack_bf(f2, f3);
      u[2] = pack_bf(f4, f5); u[3] = pack_bf(f6, f7); }

    qa = *(const float4*)(qp1 + dof);
    qb = *(const float4*)(qp1 + dof + 4);
    f0 = featmap(qa.x); f1 = featmap(qa.y); f2 = featmap(qa.z); f3 = featmap(qa.w);
    f4 = featmap(qb.x); f5 = featmap(qb.y); f6 = featmap(qb.z); f7 = featmap(qb.w);
    dot1 += f0 * ka.x + f1 * ka.y + f2 * ka.z + f3 * ka.w
          + f4 * kb.x + f5 * kb.y + f6 * kb.z + f7 * kb.w;
    bf16x8 a1;
    { uint32_t* u = (uint32_t*)&a1;
      u[0] = pack_bf(f0, f1); u[1] = pack_bf(f2, f3);
      u[2] = pack_bf(f4, f5); u[3] = pack_bf(f6, f7); }

#pragma unroll
    for (int ct = 0; ct < 8; ++ct) {
      bf16x8 bb = *(const bf16x8*)(kvp + (size_t)((ct * 16 + lr) * 128) + dof);
      acc0[ct] = __builtin_amdgcn_mfma_f32_16x16x32_bf16(a0, bb, acc0[ct], 0, 0, 0);
      acc1[ct] = __builtin_amdgcn_mfma_f32_16x16x32_bf16(a1, bb, acc1[ct], 0, 0, 0);
    }
  }

  dot0 += __shfl_xor(dot0, 16); dot0 += __shfl_xor(dot0, 32);
  dot1 += __shfl_xor(dot1, 16); dot1 += __shfl_xor(dot1, 32);
  const float thr = thrp[0];
  float s0 = dot0 > thr ? dot0 : 0.f;
  float s1 = dot1 > thr ? dot1 : 0.f;
  const float z0 = 1.f / (s0 + 1e-6f);
  const float z1 = 1.f / (s1 + 1e-6f);

  float* op = out + ((size_t)(n * LSEQ + r0)) * NHD + h * 128;
#pragma unroll
  for (int jj = 0; jj < 4; ++jj) {
    int row = lg * 4 + jj;                 // C/D: col=lane&15, row=(lane>>4)*4+jj
    float zz0 = __shfl(z0, row);           // lanes 0..15 hold rows 0..15
    float zz1 = __shfl(z1, row);
#pragma unroll
    for (int ct = 0; ct < 8; ++ct) {
      op[(size_t)row * NHD + ct * 16 + lr]        = acc0[ct][jj] * zz0;
      op[(size_t)(row + 16) * NHD + ct * 16 + lr] = acc1[ct][jj] * zz1;
    }
  }
}

extern "C" void kernel_launch(void* const* d_in, const int* in_sizes, int n_in,
                              void* d_out, int out_size, void* d_ws, size_t ws_size,
                              hipStream_t stream) {
  const float* queries   = (const float*)d_in[0];
  const float* keys      = (const float*)d_in[1];
  const float* values    = (const float*)d_in[2];
  const float* threshold = (const float*)d_in[3];
  float* out = (float*)d_out;

  // ws: ktil 67.1MB | vtil 67.1MB | kvb 1MB | ksumg 16KB  (total ~135.3MB;
  // R4's NL==4 path proved ws_size >= 136.35MB)
  ushort_t* ktil = (ushort_t*)d_ws;
  ushort_t* vtil = ktil + (size_t)4 * 8 * 1024 * 128 * 8;
  ushort_t* kvb  = vtil + (size_t)4 * 8 * 1024 * 128 * 8;
  float* ksumg   = (float*)(kvb + (size_t)32 * 16384);

  retile8<<<dim3(1024, 4), 512, 0, stream>>>(keys, values, ktil, vtil);
  kv_heads<<<dim3(2, 8, 4), 1024, 0, stream>>>(ktil, vtil, kvb, ksumg);
  attn_out<<<dim3(64, 32), 256, 0, stream>>>(queries, kvb, ksumg, threshold, out);
}

// Round 6
// 266.855 us; speedup vs baseline: 1.8957x; 1.4527x over previous
//
#include <hip/hip_runtime.h>
#include <stdint.h>

// DynamicSparseLinearAttention on MI355X.
// N=4, L=8192, H=8, D=V=128. Layout [n][l][h][d], row stride H*D = 1024 floats.
//
// R5 lessons: (R4) atomics write through L2 -> never; (R5) 64-block grids starve
// the chip (Occ 8%) -> split-s with PRIVATE fp32 partials + tiny merge kernel.
//
// 4 launches:
//  retile2:  [n][l][h][d] fp32 -> bf16 tiles [n][h][sb(1024)][d(128)][s(8)].
//            Fused K+V staging (64KB LDS, 8 loads in flight, ONE barrier),
//            lane->d remap so tile stores are dense 1KB/wave instructions.
//  kv_split: grid (CH=8 chunks, 8 h, 4 n) = 256 blocks x 1024 thr (16 waves,
//            wave = 32d x 32v, 4 MFMA/k-step, prefetched fragments). Each block
//            writes a private fp32 partial (write-once, no atomics).
//            Ksum via extra MFMA vs all-ones B on the matrix pipe.
//  kv_merge: sum CH partials -> kvb bf16 [nh][v][d] + ksumg. 128 blocks.
//  attn_out: out[l,v] = (Qf[l,:] @ KV) * Z[l]; Z = 1/(where(s>thr,s,0)+eps);
//            score = Qf.Ksum in-register + shfl_xor. No LDS, no barriers.

#define LSEQ 8192
#define NHD  1024   // H*D

typedef __attribute__((ext_vector_type(4))) float f32x4;
typedef __attribute__((ext_vector_type(8))) short bf16x8;
typedef unsigned short ushort_t;

static __device__ __forceinline__ unsigned short f2bf(float x) {
  union { float f; uint32_t u; } v; v.f = x;
  uint32_t r = v.u + 0x7FFFu + ((v.u >> 16) & 1u);  // RNE
  return (unsigned short)(r >> 16);
}
static __device__ __forceinline__ uint32_t pack_bf(float a, float b) {
  return (uint32_t)f2bf(a) | ((uint32_t)f2bf(b) << 16);
}
static __device__ __forceinline__ float featmap(float x) {
  // elu(x)+1 = x+1 (x>0) else exp(x)
  return x > 0.f ? x + 1.f : __expf(x);
}

// ---------------- Phase 1a: retile (fused K+V, one barrier) ----------------
// Grid (1024 sb, 4 n), 512 thr. Block: 8 s-rows x 1024 hd for both K and V.
__global__ __launch_bounds__(512) void retile2(const float* __restrict__ keys,
                                               const float* __restrict__ values,
                                               ushort_t* __restrict__ ktil,
                                               ushort_t* __restrict__ vtil) {
  __shared__ float kls[8192];
  __shared__ float vls[8192];
  const int tid = threadIdx.x;
  const int sbg = blockIdx.x, n = blockIdx.y;
  const size_t gbase = ((size_t)n * LSEQ + (size_t)sbg * 8) * NHD;
  {
    const float4* kg = (const float4*)(keys + gbase);
    const float4* vg = (const float4*)(values + gbase);
    float4* kl = (float4*)kls;
    float4* vl = (float4*)vls;
#pragma unroll
    for (int i = 0; i < 4; ++i) kl[tid + i * 512] = kg[tid + i * 512];
#pragma unroll
    for (int i = 0; i < 4; ++i) vl[tid + i * 512] = vg[tid + i * 512];
  }
  __syncthreads();
  const int w = tid >> 6, l = tid & 63;       // w = h, lane l owns d=l and d=l+64
  const int col = w * 128 + l;
  const size_t ob = (((size_t)n * 8 + w) * 1024 + sbg) * 1024;  // [d(128)][s(8)] elems
  {
    uint32_t da[4], db[4];
#pragma unroll
    for (int j = 0; j < 4; ++j) {
      da[j] = pack_bf(featmap(kls[(2 * j) * 1024 + col]),
                      featmap(kls[(2 * j + 1) * 1024 + col]));
      db[j] = pack_bf(featmap(kls[(2 * j) * 1024 + col + 64]),
                      featmap(kls[(2 * j + 1) * 1024 + col + 64]));
    }
    *(uint4*)(ktil + ob + (size_t)l * 8)        = make_uint4(da[0], da[1], da[2], da[3]);
    *(uint4*)(ktil + ob + (size_t)(l + 64) * 8) = make_uint4(db[0], db[1], db[2], db[3]);
  }
  {
    uint32_t da[4], db[4];
#pragma unroll
    for (int j = 0; j < 4; ++j) {
      da[j] = pack_bf(vls[(2 * j) * 1024 + col],      vls[(2 * j + 1) * 1024 + col]);
      db[j] = pack_bf(vls[(2 * j) * 1024 + col + 64], vls[(2 * j + 1) * 1024 + col + 64]);
    }
    *(uint4*)(vtil + ob + (size_t)l * 8)        = make_uint4(da[0], da[1], da[2], da[3]);
    *(uint4*)(vtil + ob + (size_t)(l + 64) * 8) = make_uint4(db[0], db[1], db[2], db[3]);
  }
}

// ---------------- Phase 1b: split-s KV GEMM, private partials ----------------
// Grid (CH, 8 h, 4 n), 1024 thr = 16 waves = 4 wr(d) x 4 wc(v).
// Wave: d [wr*32,+32) x v [wc*32,+32) = 2x2 frags, 4 MFMA/k-step (32 s).
__global__ __launch_bounds__(1024) void kv_split(const ushort_t* __restrict__ ktil,
                                                 const ushort_t* __restrict__ vtil,
                                                 float* __restrict__ kvp,
                                                 float* __restrict__ kspart) {
  const int tid = threadIdx.x;
  const int chunk = blockIdx.x, CH = gridDim.x;
  const int h = blockIdx.y, n = blockIdx.z, nh = n * 8 + h;
  const int lane = tid & 63, w = tid >> 6;
  const int wr = w & 3, wc = w >> 2;
  const int lr = lane & 15, lg = lane >> 4;
  const int sbPer = 1024 / CH;
  const int iters = sbPer / 4;          // k-steps of 32 s
  const size_t tb = ((size_t)nh * 1024 + (size_t)chunk * sbPer) * 1024;
  const ushort_t* ka = ktil + tb + (size_t)lg * 1024 + (wr * 32 + lr) * 8;
  const ushort_t* va = vtil + tb + (size_t)lg * 1024 + (wc * 32 + lr) * 8;

  f32x4 acc[2][2] = {};
  f32x4 ak[2] = {};
  bf16x8 ones;
  { uint32_t* u = (uint32_t*)&ones; u[0] = u[1] = u[2] = u[3] = 0x3F803F80u; }

  bf16x8 a0 = *(const bf16x8*)(ka);
  bf16x8 a1 = *(const bf16x8*)(ka + 128);
  bf16x8 b0 = *(const bf16x8*)(va);
  bf16x8 b1 = *(const bf16x8*)(va + 128);
  for (int it = 0; it < iters; ++it) {
    bf16x8 na0, na1, nb0, nb1;
    if (it + 1 < iters) {
      const ushort_t* kn = ka + (size_t)(it + 1) * 4096;
      const ushort_t* vn = va + (size_t)(it + 1) * 4096;
      na0 = *(const bf16x8*)kn;  na1 = *(const bf16x8*)(kn + 128);
      nb0 = *(const bf16x8*)vn;  nb1 = *(const bf16x8*)(vn + 128);
    }
    acc[0][0] = __builtin_amdgcn_mfma_f32_16x16x32_bf16(a0, b0, acc[0][0], 0, 0, 0);
    acc[0][1] = __builtin_amdgcn_mfma_f32_16x16x32_bf16(a0, b1, acc[0][1], 0, 0, 0);
    acc[1][0] = __builtin_amdgcn_mfma_f32_16x16x32_bf16(a1, b0, acc[1][0], 0, 0, 0);
    acc[1][1] = __builtin_amdgcn_mfma_f32_16x16x32_bf16(a1, b1, acc[1][1], 0, 0, 0);
    if (wc == 0) {
      ak[0] = __builtin_amdgcn_mfma_f32_16x16x32_bf16(a0, ones, ak[0], 0, 0, 0);
      ak[1] = __builtin_amdgcn_mfma_f32_16x16x32_bf16(a1, ones, ak[1], 0, 0, 0);
    }
    a0 = na0; a1 = na1; b0 = nb0; b1 = nb1;
  }

  // C/D: col(v)=lane&15, row(d)=(lane>>4)*4+j. Private partial, write-once.
  float* dst = kvp + ((size_t)chunk * 32 + nh) * 16384;
#pragma unroll
  for (int fr = 0; fr < 2; ++fr)
#pragma unroll
    for (int fc = 0; fc < 2; ++fc) {
      int d0 = wr * 32 + fr * 16 + lg * 4;
      int v  = wc * 32 + fc * 16 + lr;
      *(float4*)(dst + (size_t)v * 128 + d0) =
          make_float4(acc[fr][fc][0], acc[fr][fc][1], acc[fr][fc][2], acc[fr][fc][3]);
    }
  if (wc == 0 && lr == 0) {
    float* ks = kspart + ((size_t)chunk * 32 + nh) * 128;
#pragma unroll
    for (int fr = 0; fr < 2; ++fr)
      *(float4*)(ks + wr * 32 + fr * 16 + lg * 4) =
          make_float4(ak[fr][0], ak[fr][1], ak[fr][2], ak[fr][3]);
  }
}

// ---------------- Phase 1c: merge partials ----------------
// Grid (32 nh, 4 q), 256 thr. Sums CH partials -> kvb bf16 + ksumg.
__global__ __launch_bounds__(256) void kv_merge(const float* __restrict__ kvp,
                                                const float* __restrict__ kspart,
                                                ushort_t* __restrict__ kvb,
                                                float* __restrict__ ksumg,
                                                int CH) {
  const int nh = blockIdx.x, q = blockIdx.y, tid = threadIdx.x;
  const size_t off = (size_t)nh * 16384 + q * 4096;
#pragma unroll
  for (int i = 0; i < 4; ++i) {
    size_t idx = off + (size_t)(i * 256 + tid) * 4;
    f32x4 s = {};
    for (int c = 0; c < CH; ++c)
      s += *(const f32x4*)(kvp + (size_t)c * 524288 + idx);
    *(uint2*)(kvb + idx) = make_uint2(pack_bf(s[0], s[1]), pack_bf(s[2], s[3]));
  }
  if (q == 0 && tid < 128) {
    float s = 0.f;
    for (int c = 0; c < CH; ++c) s += kspart[((size_t)c * 32 + nh) * 128 + tid];
    ksumg[nh * 128 + tid] = s;
  }
}

// ---------------- Phase 2: no-LDS register-direct ----------------
// Grid (64 mc, 32 nh), 256 thr = 4 waves; wave w owns rows mc*128+w*32..+32.
__global__ __launch_bounds__(256, 4) void attn_out(const float* __restrict__ q,
                                                   const ushort_t* __restrict__ kvb,
                                                   const float* __restrict__ ksumg,
                                                   const float* __restrict__ thrp,
                                                   float* __restrict__ out) {
  const int tid = threadIdx.x;
  const int mc = blockIdx.x, nh = blockIdx.y;
  const int n = nh >> 3, h = nh & 7;
  const int lane = tid & 63, w = tid >> 6;
  const int lr = lane & 15, lg = lane >> 4;
  const int r0 = mc * 128 + w * 32;

  const float* qp0 = q + ((size_t)(n * LSEQ + r0 + lr)) * NHD + h * 128;
  const float* qp1 = qp0 + (size_t)16 * NHD;
  const float* ksp = ksumg + nh * 128 + lg * 8;
  const ushort_t* kvp = kvb + (size_t)nh * 16384;   // [v][d] bf16

  f32x4 acc0[8] = {};
  f32x4 acc1[8] = {};
  float dot0 = 0.f, dot1 = 0.f;

#pragma unroll
  for (int ks = 0; ks < 4; ++ks) {
    const int dof = ks * 32 + lg * 8;
    float4 ka = *(const float4*)(ksp + ks * 32);
    float4 kb = *(const float4*)(ksp + ks * 32 + 4);

    float4 qa = *(const float4*)(qp0 + dof);
    float4 qb = *(const float4*)(qp0 + dof + 4);
    float f0 = featmap(qa.x), f1 = featmap(qa.y), f2 = featmap(qa.z), f3 = featmap(qa.w);
    float f4 = featmap(qb.x), f5 = featmap(qb.y), f6 = featmap(qb.z), f7 = featmap(qb.w);
    dot0 += f0 * ka.x + f1 * ka.y + f2 * ka.z + f3 * ka.w
          + f4 * kb.x + f5 * kb.y + f6 * kb.z + f7 * kb.w;
    bf16x8 a0;
    { uint32_t* u = (uint32_t*)&a0;
      u[0] = pack_bf(f0, f1); u[1] = pack_bf(f2, f3);
      u[2] = pack_bf(f4, f5); u[3] = pack_bf(f6, f7); }

    qa = *(const float4*)(qp1 + dof);
    qb = *(const float4*)(qp1 + dof + 4);
    f0 = featmap(qa.x); f1 = featmap(qa.y); f2 = featmap(qa.z); f3 = featmap(qa.w);
    f4 = featmap(qb.x); f5 = featmap(qb.y); f6 = featmap(qb.z); f7 = featmap(qb.w);
    dot1 += f0 * ka.x + f1 * ka.y + f2 * ka.z + f3 * ka.w
          + f4 * kb.x + f5 * kb.y + f6 * kb.z + f7 * kb.w;
    bf16x8 a1;
    { uint32_t* u = (uint32_t*)&a1;
      u[0] = pack_bf(f0, f1); u[1] = pack_bf(f2, f3);
      u[2] = pack_bf(f4, f5); u[3] = pack_bf(f6, f7); }

#pragma unroll
    for (int ct = 0; ct < 8; ++ct) {
      bf16x8 bb = *(const bf16x8*)(kvp + (size_t)((ct * 16 + lr) * 128) + dof);
      acc0[ct] = __builtin_amdgcn_mfma_f32_16x16x32_bf16(a0, bb, acc0[ct], 0, 0, 0);
      acc1[ct] = __builtin_amdgcn_mfma_f32_16x16x32_bf16(a1, bb, acc1[ct], 0, 0, 0);
    }
  }

  dot0 += __shfl_xor(dot0, 16); dot0 += __shfl_xor(dot0, 32);
  dot1 += __shfl_xor(dot1, 16); dot1 += __shfl_xor(dot1, 32);
  const float thr = thrp[0];
  float s0 = dot0 > thr ? dot0 : 0.f;
  float s1 = dot1 > thr ? dot1 : 0.f;
  const float z0 = 1.f / (s0 + 1e-6f);
  const float z1 = 1.f / (s1 + 1e-6f);

  float* op = out + ((size_t)(n * LSEQ + r0)) * NHD + h * 128;
#pragma unroll
  for (int jj = 0; jj < 4; ++jj) {
    int row = lg * 4 + jj;                 // C/D: col=lane&15, row=(lane>>4)*4+jj
    float zz0 = __shfl(z0, row);           // lanes 0..15 hold rows 0..15
    float zz1 = __shfl(z1, row);
#pragma unroll
    for (int ct = 0; ct < 8; ++ct) {
      op[(size_t)row * NHD + ct * 16 + lr]        = acc0[ct][jj] * zz0;
      op[(size_t)(row + 16) * NHD + ct * 16 + lr] = acc1[ct][jj] * zz1;
    }
  }
}

extern "C" void kernel_launch(void* const* d_in, const int* in_sizes, int n_in,
                              void* d_out, int out_size, void* d_ws, size_t ws_size,
                              hipStream_t stream) {
  const float* queries   = (const float*)d_in[0];
  const float* keys      = (const float*)d_in[1];
  const float* values    = (const float*)d_in[2];
  const float* threshold = (const float*)d_in[3];
  float* out = (float*)d_out;

  // ws: ktil 67.1MB | vtil 67.1MB | kvb 1MB | ksumg 16KB | kvp CH*2MB | kspart CH*16KB
  const size_t tilElems = (size_t)4 * 8 * 1024 * 1024;   // bf16 elems per tensor
  ushort_t* ktil = (ushort_t*)d_ws;
  ushort_t* vtil = ktil + tilElems;
  ushort_t* kvb  = vtil + tilElems;
  float* ksumg   = (float*)(kvb + (size_t)32 * 16384);
  float* kvp     = ksumg + 32 * 128;
  float* kspart_base = kvp;  // kspart placed after kvp once CH chosen

  const size_t fixedB = 2 * tilElems * 2 + (size_t)32 * 16384 * 2 + (size_t)32 * 128 * 4;
  int CH = 8;
  while (CH > 1 && fixedB + (size_t)CH * (524288 + 32 * 128) * 4 > ws_size) CH >>= 1;
  float* kspart = kvp + (size_t)CH * 524288;
  (void)kspart_base;

  retile2<<<dim3(1024, 4), 512, 0, stream>>>(keys, values, ktil, vtil);
  kv_split<<<dim3(CH, 8, 4), 1024, 0, stream>>>(ktil, vtil, kvp, kspart);
  kv_merge<<<dim3(32, 4), 256, 0, stream>>>(kvp, kspart, kvb, ksumg, CH);
  attn_out<<<dim3(64, 32), 256, 0, stream>>>(queries, kvb, ksumg, threshold, out);
}

// Round 7
// 223.167 us; speedup vs baseline: 2.2668x; 1.1958x over previous
//
#include <hip/hip_runtime.h>
#include <stdint.h>

// DynamicSparseLinearAttention on MI355X.
// N=4, L=8192, H=8, D=V=128. Layout [n][l][h][d], row stride H*D = 1024 floats.
//
// Lessons: (R4) atomics write through L2 -> never. (R5) 64-block grids starve
// the chip. (R6) per-lane 16B loads at 4KB stride thrash L2 -> 2.3x write
// amplification; LDS-staged coalesced reads keep FETCH/WRITE at ideal (R3).
//
// 4 launches:
//  retile2:  [n][l][h][d] fp32 -> bf16 tiles [n][h][sb(1024)][d(128)][s(8)].
//            Fused K+V staging (64KB LDS, ONE barrier), dense 1KB/wave stores.
//  kv_split: (CH,8,4) blocks x 1024 thr; wave = 32d x 32v, prefetched frags;
//            private fp32 partials (write-once). Ksum via ones-MFMA.
//  kv_merge: sum CH partials -> kvb bf16 [nh][v][d] + ksumg.
//  attn_out: Q staged to LDS bf16 (coalesced 512B reads, row*17 padded layout
//            -> conflict-free b128 frag reads); score done DURING staging in
//            fp32 regs + shfl_xor reduce; B-frags direct from L2-hot kvb;
//            R3-proven store pattern. One barrier, 35KB LDS, 4 blocks/CU.

#define LSEQ 8192
#define NHD  1024   // H*D

typedef __attribute__((ext_vector_type(4))) float f32x4;
typedef __attribute__((ext_vector_type(8))) short bf16x8;
typedef unsigned short ushort_t;

static __device__ __forceinline__ unsigned short f2bf(float x) {
  union { float f; uint32_t u; } v; v.f = x;
  uint32_t r = v.u + 0x7FFFu + ((v.u >> 16) & 1u);  // RNE
  return (unsigned short)(r >> 16);
}
static __device__ __forceinline__ uint32_t pack_bf(float a, float b) {
  return (uint32_t)f2bf(a) | ((uint32_t)f2bf(b) << 16);
}
static __device__ __forceinline__ float featmap(float x) {
  // elu(x)+1 = x+1 (x>0) else exp(x)
  return x > 0.f ? x + 1.f : __expf(x);
}

// ---------------- Phase 1a: retile (fused K+V, one barrier) ----------------
__global__ __launch_bounds__(512) void retile2(const float* __restrict__ keys,
                                               const float* __restrict__ values,
                                               ushort_t* __restrict__ ktil,
                                               ushort_t* __restrict__ vtil) {
  __shared__ float kls[8192];
  __shared__ float vls[8192];
  const int tid = threadIdx.x;
  const int sbg = blockIdx.x, n = blockIdx.y;
  const size_t gbase = ((size_t)n * LSEQ + (size_t)sbg * 8) * NHD;
  {
    const float4* kg = (const float4*)(keys + gbase);
    const float4* vg = (const float4*)(values + gbase);
    float4* kl = (float4*)kls;
    float4* vl = (float4*)vls;
#pragma unroll
    for (int i = 0; i < 4; ++i) kl[tid + i * 512] = kg[tid + i * 512];
#pragma unroll
    for (int i = 0; i < 4; ++i) vl[tid + i * 512] = vg[tid + i * 512];
  }
  __syncthreads();
  const int w = tid >> 6, l = tid & 63;       // w = h, lane l owns d=l and d=l+64
  const int col = w * 128 + l;
  const size_t ob = (((size_t)n * 8 + w) * 1024 + sbg) * 1024;  // [d(128)][s(8)]
  {
    uint32_t da[4], db[4];
#pragma unroll
    for (int j = 0; j < 4; ++j) {
      da[j] = pack_bf(featmap(kls[(2 * j) * 1024 + col]),
                      featmap(kls[(2 * j + 1) * 1024 + col]));
      db[j] = pack_bf(featmap(kls[(2 * j) * 1024 + col + 64]),
                      featmap(kls[(2 * j + 1) * 1024 + col + 64]));
    }
    *(uint4*)(ktil + ob + (size_t)l * 8)        = make_uint4(da[0], da[1], da[2], da[3]);
    *(uint4*)(ktil + ob + (size_t)(l + 64) * 8) = make_uint4(db[0], db[1], db[2], db[3]);
  }
  {
    uint32_t da[4], db[4];
#pragma unroll
    for (int j = 0; j < 4; ++j) {
      da[j] = pack_bf(vls[(2 * j) * 1024 + col],      vls[(2 * j + 1) * 1024 + col]);
      db[j] = pack_bf(vls[(2 * j) * 1024 + col + 64], vls[(2 * j + 1) * 1024 + col + 64]);
    }
    *(uint4*)(vtil + ob + (size_t)l * 8)        = make_uint4(da[0], da[1], da[2], da[3]);
    *(uint4*)(vtil + ob + (size_t)(l + 64) * 8) = make_uint4(db[0], db[1], db[2], db[3]);
  }
}

// ---------------- Phase 1b: split-s KV GEMM, private partials ----------------
__global__ __launch_bounds__(1024) void kv_split(const ushort_t* __restrict__ ktil,
                                                 const ushort_t* __restrict__ vtil,
                                                 float* __restrict__ kvp,
                                                 float* __restrict__ kspart) {
  const int tid = threadIdx.x;
  const int chunk = blockIdx.x, CH = gridDim.x;
  const int h = blockIdx.y, n = blockIdx.z, nh = n * 8 + h;
  const int lane = tid & 63, w = tid >> 6;
  const int wr = w & 3, wc = w >> 2;
  const int lr = lane & 15, lg = lane >> 4;
  const int sbPer = 1024 / CH;
  const int iters = sbPer / 4;          // k-steps of 32 s
  const size_t tb = ((size_t)nh * 1024 + (size_t)chunk * sbPer) * 1024;
  const ushort_t* ka = ktil + tb + (size_t)lg * 1024 + (wr * 32 + lr) * 8;
  const ushort_t* va = vtil + tb + (size_t)lg * 1024 + (wc * 32 + lr) * 8;

  f32x4 acc[2][2] = {};
  f32x4 ak[2] = {};
  bf16x8 ones;
  { uint32_t* u = (uint32_t*)&ones; u[0] = u[1] = u[2] = u[3] = 0x3F803F80u; }

  bf16x8 a0 = *(const bf16x8*)(ka);
  bf16x8 a1 = *(const bf16x8*)(ka + 128);
  bf16x8 b0 = *(const bf16x8*)(va);
  bf16x8 b1 = *(const bf16x8*)(va + 128);
  for (int it = 0; it < iters; ++it) {
    bf16x8 na0, na1, nb0, nb1;
    if (it + 1 < iters) {
      const ushort_t* kn = ka + (size_t)(it + 1) * 4096;
      const ushort_t* vn = va + (size_t)(it + 1) * 4096;
      na0 = *(const bf16x8*)kn;  na1 = *(const bf16x8*)(kn + 128);
      nb0 = *(const bf16x8*)vn;  nb1 = *(const bf16x8*)(vn + 128);
    }
    acc[0][0] = __builtin_amdgcn_mfma_f32_16x16x32_bf16(a0, b0, acc[0][0], 0, 0, 0);
    acc[0][1] = __builtin_amdgcn_mfma_f32_16x16x32_bf16(a0, b1, acc[0][1], 0, 0, 0);
    acc[1][0] = __builtin_amdgcn_mfma_f32_16x16x32_bf16(a1, b0, acc[1][0], 0, 0, 0);
    acc[1][1] = __builtin_amdgcn_mfma_f32_16x16x32_bf16(a1, b1, acc[1][1], 0, 0, 0);
    if (wc == 0) {
      ak[0] = __builtin_amdgcn_mfma_f32_16x16x32_bf16(a0, ones, ak[0], 0, 0, 0);
      ak[1] = __builtin_amdgcn_mfma_f32_16x16x32_bf16(a1, ones, ak[1], 0, 0, 0);
    }
    a0 = na0; a1 = na1; b0 = nb0; b1 = nb1;
  }

  float* dst = kvp + ((size_t)chunk * 32 + nh) * 16384;
#pragma unroll
  for (int fr = 0; fr < 2; ++fr)
#pragma unroll
    for (int fc = 0; fc < 2; ++fc) {
      int d0 = wr * 32 + fr * 16 + lg * 4;
      int v  = wc * 32 + fc * 16 + lr;
      *(float4*)(dst + (size_t)v * 128 + d0) =
          make_float4(acc[fr][fc][0], acc[fr][fc][1], acc[fr][fc][2], acc[fr][fc][3]);
    }
  if (wc == 0 && lr == 0) {
    float* ks = kspart + ((size_t)chunk * 32 + nh) * 128;
#pragma unroll
    for (int fr = 0; fr < 2; ++fr)
      *(float4*)(ks + wr * 32 + fr * 16 + lg * 4) =
          make_float4(ak[fr][0], ak[fr][1], ak[fr][2], ak[fr][3]);
  }
}

// ---------------- Phase 1c: merge partials ----------------
__global__ __launch_bounds__(256) void kv_merge(const float* __restrict__ kvp,
                                                const float* __restrict__ kspart,
                                                ushort_t* __restrict__ kvb,
                                                float* __restrict__ ksumg,
                                                int CH) {
  const int nh = blockIdx.x, q = blockIdx.y, tid = threadIdx.x;
  const size_t off = (size_t)nh * 16384 + q * 4096;
#pragma unroll
  for (int i = 0; i < 4; ++i) {
    size_t idx = off + (size_t)(i * 256 + tid) * 4;
    f32x4 s = {};
    for (int c = 0; c < CH; ++c)
      s += *(const f32x4*)(kvp + (size_t)c * 524288 + idx);
    *(uint2*)(kvb + idx) = make_uint2(pack_bf(s[0], s[1]), pack_bf(s[2], s[3]));
  }
  if (q == 0 && tid < 128) {
    float s = 0.f;
    for (int c = 0; c < CH; ++c) s += kspart[((size_t)c * 32 + nh) * 128 + tid];
    ksumg[nh * 128 + tid] = s;
  }
}

// ---------------- Phase 2: LDS-staged Q + direct-global B ----------------
// Grid (64 mc, 32 nh), 256 thr = 4 waves; wave w owns rows w*32..+32 of the
// 128-row tile. As layout: chunk = row*17 + c8 (16B chunks, +1 pad kills bank
// conflicts for both staging writes and b128 frag reads). Score computed
// during staging (fp32, pre-rounding) via shfl_xor over the 32-lane row group.
__global__ __launch_bounds__(256, 4) void attn_out(const float* __restrict__ q,
                                                   const ushort_t* __restrict__ kvb,
                                                   const float* __restrict__ ksumg,
                                                   const float* __restrict__ thrp,
                                                   float* __restrict__ out) {
  __shared__ __align__(16) uint32_t As[128 * 17 * 4];  // 34.8KB
  __shared__ float zrow[128];

  const int tid = threadIdx.x;
  const int mc = blockIdx.x, nh = blockIdx.y;
  const int n = nh >> 3, h = nh & 7;
  const size_t qoff = ((size_t)(n * LSEQ + mc * 128)) * NHD + h * 128;
  const float thr = thrp[0];

  // ksum slice for this thread's staging column (c4 = tid&31, constant)
  const int c4 = tid & 31;
  const float4 kk = *(const float4*)(ksumg + nh * 128 + c4 * 4);

  // ---- stage Qf -> As (bf16) + fp32 score on the fly ----
#pragma unroll
  for (int it = 0; it < 16; ++it) {
    int rr = it * 8 + (tid >> 5);
    float4 qv = *(const float4*)(q + qoff + (size_t)rr * NHD + c4 * 4);
    float f0 = featmap(qv.x), f1 = featmap(qv.y), f2 = featmap(qv.z), f3 = featmap(qv.w);
    uint32_t* dst = &As[(rr * 17 + (c4 >> 1)) * 4 + (c4 & 1) * 2];
    dst[0] = pack_bf(f0, f1);
    dst[1] = pack_bf(f2, f3);
    float p = f0 * kk.x + f1 * kk.y + f2 * kk.z + f3 * kk.w;
    p += __shfl_xor(p, 1);  p += __shfl_xor(p, 2);  p += __shfl_xor(p, 4);
    p += __shfl_xor(p, 8);  p += __shfl_xor(p, 16);
    if (c4 == 0) {
      float sp = p > thr ? p : 0.f;
      zrow[rr] = 1.f / (sp + 1e-6f);
    }
  }
  __syncthreads();

  // ---- MFMA: A from LDS, B direct from kvb (L2-hot 32KB) ----
  const int lane = tid & 63;
  const int w = tid >> 6;
  const int lr = lane & 15, lg = lane >> 4;
  const ushort_t* kvp = kvb + (size_t)nh * 16384;   // [v][d] bf16

  f32x4 acc0[8] = {};
  f32x4 acc1[8] = {};
#pragma unroll
  for (int ks = 0; ks < 4; ++ks) {
    const int c8 = ks * 4 + lg;
    const int dof = ks * 32 + lg * 8;
    const int r0 = w * 32 + lr;
    bf16x8 a0 = *(const bf16x8*)&As[(r0 * 17 + c8) * 4];
    bf16x8 a1 = *(const bf16x8*)&As[((r0 + 16) * 17 + c8) * 4];
#pragma unroll
    for (int ct = 0; ct < 8; ++ct) {
      bf16x8 bb = *(const bf16x8*)(kvp + (size_t)((ct * 16 + lr) * 128) + dof);
      acc0[ct] = __builtin_amdgcn_mfma_f32_16x16x32_bf16(a0, bb, acc0[ct], 0, 0, 0);
      acc1[ct] = __builtin_amdgcn_mfma_f32_16x16x32_bf16(a1, bb, acc1[ct], 0, 0, 0);
    }
  }

  float z0[4], z1[4];
#pragma unroll
  for (int j = 0; j < 4; ++j) {
    z0[j] = zrow[w * 32 + lg * 4 + j];
    z1[j] = zrow[w * 32 + 16 + lg * 4 + j];
  }
  float* op = out + qoff;
#pragma unroll
  for (int ct = 0; ct < 8; ++ct)
#pragma unroll
    for (int jj = 0; jj < 4; ++jj) {
      int row = w * 32 + lg * 4 + jj;   // C/D: col=lane&15, row=(lane>>4)*4+jj
      op[(size_t)row * NHD + ct * 16 + lr]        = acc0[ct][jj] * z0[jj];
      op[(size_t)(row + 16) * NHD + ct * 16 + lr] = acc1[ct][jj] * z1[jj];
    }
}

extern "C" void kernel_launch(void* const* d_in, const int* in_sizes, int n_in,
                              void* d_out, int out_size, void* d_ws, size_t ws_size,
                              hipStream_t stream) {
  const float* queries   = (const float*)d_in[0];
  const float* keys      = (const float*)d_in[1];
  const float* values    = (const float*)d_in[2];
  const float* threshold = (const float*)d_in[3];
  float* out = (float*)d_out;

  // ws: ktil 67.1MB | vtil 67.1MB | kvb 1MB | ksumg 16KB | kvp CH*2MB | kspart CH*16KB
  const size_t tilElems = (size_t)4 * 8 * 1024 * 1024;   // bf16 elems per tensor
  ushort_t* ktil = (ushort_t*)d_ws;
  ushort_t* vtil = ktil + tilElems;
  ushort_t* kvb  = vtil + tilElems;
  float* ksumg   = (float*)(kvb + (size_t)32 * 16384);
  float* kvp     = ksumg + 32 * 128;

  const size_t fixedB = 2 * tilElems * 2 + (size_t)32 * 16384 * 2 + (size_t)32 * 128 * 4;
  int CH = 8;
  while (CH > 1 && fixedB + (size_t)CH * (524288 + 32 * 128) * 4 > ws_size) CH >>= 1;
  float* kspart = kvp + (size_t)CH * 524288;

  retile2<<<dim3(1024, 4), 512, 0, stream>>>(keys, values, ktil, vtil);
  kv_split<<<dim3(CH, 8, 4), 1024, 0, stream>>>(ktil, vtil, kvp, kspart);
  kv_merge<<<dim3(32, 4), 256, 0, stream>>>(kvp, kspart, kvb, ksumg, CH);
  attn_out<<<dim3(64, 32), 256, 0, stream>>>(queries, kvb, ksumg, threshold, out);
}

// Round 8
// 193.898 us; speedup vs baseline: 2.6089x; 1.1510x over previous
//
#include <hip/hip_runtime.h>
#include <stdint.h>

// DynamicSparseLinearAttention on MI355X.
// N=4, L=8192, H=8, D=V=128. Layout [n][l][h][d], row stride H*D = 1024 floats.
//
// Lessons: (R4) atomics write through L2 -> never. (R5) small grids starve the
// chip. (R6) per-lane 16B loads at 4KB stride thrash L2 -> amplification; LDS
// staging with coalesced reads is mandatory. (R7) tile pipeline moves K/V 3x;
// L3 absorbs 1/8-dense per-(n,h) reads when all 8 h-blocks run concurrently.
//
// 3 launches:
//  kv_direct: fused retile+GEMM. Grid (CH=16,8,4)=512 blocks x 512 thr (8 waves
//             = 2d x 4v). Per 32-s step: stage K(featmap,f32)/V into padded LDS
//             [32][136] (2-way conflicts only), register-prefetch next step,
//             transposed fragment reads + bf16 MFMA. Private fp32 partials,
//             write-once, no atomics. Ksum via ones-MFMA on wc==0 waves.
//  kv_merge:  sum CH partials -> kvb bf16 [nh][v][d] + ksumg.
//  attn_out:  Q staged to LDS bf16 (row*17 padded chunks), score during staging
//             (fp32 + shfl_xor), B-frags direct from L2-hot kvb, R3-proven
//             store pattern. One barrier, 35KB LDS.

#define LSEQ 8192
#define NHD  1024   // H*D

typedef __attribute__((ext_vector_type(4))) float f32x4;
typedef __attribute__((ext_vector_type(8))) short bf16x8;
typedef unsigned short ushort_t;

static __device__ __forceinline__ unsigned short f2bf(float x) {
  union { float f; uint32_t u; } v; v.f = x;
  uint32_t r = v.u + 0x7FFFu + ((v.u >> 16) & 1u);  // RNE
  return (unsigned short)(r >> 16);
}
static __device__ __forceinline__ uint32_t pack_bf(float a, float b) {
  return (uint32_t)f2bf(a) | ((uint32_t)f2bf(b) << 16);
}
static __device__ __forceinline__ float featmap(float x) {
  // elu(x)+1 = x+1 (x>0) else exp(x)
  return x > 0.f ? x + 1.f : __expf(x);
}

#define LPAD 136   // LDS row stride (floats): (s*136+d)%32 = (16*lg'+2j+d)%32 -> 2-way max

// ---------------- Phase 1: fused retile + KV GEMM ----------------
// Grid (CH, 8 h, 4 n), 512 thr = 8 waves = 2 wr(d64) x 4 wc(v32).
__global__ __launch_bounds__(512) void kv_direct(const float* __restrict__ keys,
                                                 const float* __restrict__ values,
                                                 float* __restrict__ kvp,
                                                 float* __restrict__ kspart) {
  __shared__ float kls[32 * LPAD];
  __shared__ float vls[32 * LPAD];
  const int tid = threadIdx.x;
  const int chunk = blockIdx.x, CH = gridDim.x;
  const int h = blockIdx.y, n = blockIdx.z, nh = n * 8 + h;
  const int lane = tid & 63, w = tid >> 6;
  const int wr = w >> 2, wc = w & 3;
  const int lr = lane & 15, lg = lane >> 4;
  const int sPer = LSEQ / CH;        // 512 at CH=16
  const int steps = sPer / 32;

  const size_t gb = ((size_t)n * LSEQ + (size_t)chunk * sPer) * NHD + h * 128;
  const float* gk = keys + gb;
  const float* gv = values + gb;

  const int srow = tid >> 5;         // 0..15 (it adds 16)
  const int c4 = tid & 31;

  f32x4 acc[4][2] = {};
  f32x4 ak[4] = {};
  bf16x8 ones;
  { uint32_t* u = (uint32_t*)&ones; u[0] = u[1] = u[2] = u[3] = 0x3F803F80u; }

  float4 kr[2], vr[2];
#pragma unroll
  for (int it = 0; it < 2; ++it) {
    size_t off = (size_t)(it * 16 + srow) * NHD + c4 * 4;
    kr[it] = *(const float4*)(gk + off);
    vr[it] = *(const float4*)(gv + off);
  }

  for (int t = 0; t < steps; ++t) {
    // write staged regs -> LDS (featmap K here, fp32)
#pragma unroll
    for (int it = 0; it < 2; ++it) {
      int s = it * 16 + srow;
      float4 kf = kr[it];
      kf.x = featmap(kf.x); kf.y = featmap(kf.y);
      kf.z = featmap(kf.z); kf.w = featmap(kf.w);
      *(float4*)&kls[s * LPAD + c4 * 4] = kf;
      *(float4*)&vls[s * LPAD + c4 * 4] = vr[it];
    }
    __syncthreads();
    if (t + 1 < steps) {   // issue next step's loads; they complete under MFMA
#pragma unroll
      for (int it = 0; it < 2; ++it) {
        size_t off = (size_t)((t + 1) * 32 + it * 16 + srow) * NHD + c4 * 4;
        kr[it] = *(const float4*)(gk + off);
        vr[it] = *(const float4*)(gv + off);
      }
    }
    // transposed fragment reads + pack + MFMA
    bf16x8 af[4], bfr[2];
#pragma unroll
    for (int fr = 0; fr < 4; ++fr) {
      int d = wr * 64 + fr * 16 + lr;
      float f[8];
#pragma unroll
      for (int j = 0; j < 8; ++j) f[j] = kls[(lg * 8 + j) * LPAD + d];
      uint32_t* u = (uint32_t*)&af[fr];
      u[0] = pack_bf(f[0], f[1]); u[1] = pack_bf(f[2], f[3]);
      u[2] = pack_bf(f[4], f[5]); u[3] = pack_bf(f[6], f[7]);
    }
#pragma unroll
    for (int fc = 0; fc < 2; ++fc) {
      int v = wc * 32 + fc * 16 + lr;
      float f[8];
#pragma unroll
      for (int j = 0; j < 8; ++j) f[j] = vls[(lg * 8 + j) * LPAD + v];
      uint32_t* u = (uint32_t*)&bfr[fc];
      u[0] = pack_bf(f[0], f[1]); u[1] = pack_bf(f[2], f[3]);
      u[2] = pack_bf(f[4], f[5]); u[3] = pack_bf(f[6], f[7]);
    }
#pragma unroll
    for (int fr = 0; fr < 4; ++fr)
#pragma unroll
      for (int fc = 0; fc < 2; ++fc)
        acc[fr][fc] = __builtin_amdgcn_mfma_f32_16x16x32_bf16(af[fr], bfr[fc], acc[fr][fc], 0, 0, 0);
    if (wc == 0) {
#pragma unroll
      for (int fr = 0; fr < 4; ++fr)
        ak[fr] = __builtin_amdgcn_mfma_f32_16x16x32_bf16(af[fr], ones, ak[fr], 0, 0, 0);
    }
    __syncthreads();
  }

  // C/D: col(v)=lane&15, row(d)=(lane>>4)*4+j. Private partial, write-once.
  float* dst = kvp + ((size_t)chunk * 32 + nh) * 16384;
#pragma unroll
  for (int fr = 0; fr < 4; ++fr)
#pragma unroll
    for (int fc = 0; fc < 2; ++fc) {
      int d0 = wr * 64 + fr * 16 + lg * 4;
      int v  = wc * 32 + fc * 16 + lr;
      *(float4*)(dst + (size_t)v * 128 + d0) =
          make_float4(acc[fr][fc][0], acc[fr][fc][1], acc[fr][fc][2], acc[fr][fc][3]);
    }
  if (wc == 0 && lr == 0) {
    float* ks = kspart + ((size_t)chunk * 32 + nh) * 128;
#pragma unroll
    for (int fr = 0; fr < 4; ++fr)
      *(float4*)(ks + wr * 64 + fr * 16 + lg * 4) =
          make_float4(ak[fr][0], ak[fr][1], ak[fr][2], ak[fr][3]);
  }
}

// ---------------- Phase 1c: merge partials ----------------
__global__ __launch_bounds__(256) void kv_merge(const float* __restrict__ kvp,
                                                const float* __restrict__ kspart,
                                                ushort_t* __restrict__ kvb,
                                                float* __restrict__ ksumg,
                                                int CH) {
  const int nh = blockIdx.x, q = blockIdx.y, tid = threadIdx.x;
  const size_t off = (size_t)nh * 16384 + q * 4096;
#pragma unroll
  for (int i = 0; i < 4; ++i) {
    size_t idx = off + (size_t)(i * 256 + tid) * 4;
    f32x4 s = {};
    for (int c = 0; c < CH; ++c)
      s += *(const f32x4*)(kvp + (size_t)c * 524288 + idx);
    *(uint2*)(kvb + idx) = make_uint2(pack_bf(s[0], s[1]), pack_bf(s[2], s[3]));
  }
  if (q == 0 && tid < 128) {
    float s = 0.f;
    for (int c = 0; c < CH; ++c) s += kspart[((size_t)c * 32 + nh) * 128 + tid];
    ksumg[nh * 128 + tid] = s;
  }
}

// ---------------- Phase 2: LDS-staged Q + direct-global B ----------------
__global__ __launch_bounds__(256, 4) void attn_out(const float* __restrict__ q,
                                                   const ushort_t* __restrict__ kvb,
                                                   const float* __restrict__ ksumg,
                                                   const float* __restrict__ thrp,
                                                   float* __restrict__ out) {
  __shared__ __align__(16) uint32_t As[128 * 17 * 4];  // 34.8KB
  __shared__ float zrow[128];

  const int tid = threadIdx.x;
  const int mc = blockIdx.x, nh = blockIdx.y;
  const int n = nh >> 3, h = nh & 7;
  const size_t qoff = ((size_t)(n * LSEQ + mc * 128)) * NHD + h * 128;
  const float thr = thrp[0];

  const int c4 = tid & 31;
  const float4 kk = *(const float4*)(ksumg + nh * 128 + c4 * 4);

  // ---- stage Qf -> As (bf16) + fp32 score on the fly ----
#pragma unroll
  for (int it = 0; it < 16; ++it) {
    int rr = it * 8 + (tid >> 5);
    float4 qv = *(const float4*)(q + qoff + (size_t)rr * NHD + c4 * 4);
    float f0 = featmap(qv.x), f1 = featmap(qv.y), f2 = featmap(qv.z), f3 = featmap(qv.w);
    uint32_t* dst = &As[(rr * 17 + (c4 >> 1)) * 4 + (c4 & 1) * 2];
    dst[0] = pack_bf(f0, f1);
    dst[1] = pack_bf(f2, f3);
    float p = f0 * kk.x + f1 * kk.y + f2 * kk.z + f3 * kk.w;
    p += __shfl_xor(p, 1);  p += __shfl_xor(p, 2);  p += __shfl_xor(p, 4);
    p += __shfl_xor(p, 8);  p += __shfl_xor(p, 16);
    if (c4 == 0) {
      float sp = p > thr ? p : 0.f;
      zrow[rr] = 1.f / (sp + 1e-6f);
    }
  }
  __syncthreads();

  // ---- MFMA: A from LDS, B direct from kvb (L2-hot 32KB) ----
  const int lane = tid & 63;
  const int w = tid >> 6;
  const int lr = lane & 15, lg = lane >> 4;
  const ushort_t* kvp = kvb + (size_t)nh * 16384;   // [v][d] bf16

  f32x4 acc0[8] = {};
  f32x4 acc1[8] = {};
#pragma unroll
  for (int ks = 0; ks < 4; ++ks) {
    const int c8 = ks * 4 + lg;
    const int dof = ks * 32 + lg * 8;
    const int r0 = w * 32 + lr;
    bf16x8 a0 = *(const bf16x8*)&As[(r0 * 17 + c8) * 4];
    bf16x8 a1 = *(const bf16x8*)&As[((r0 + 16) * 17 + c8) * 4];
#pragma unroll
    for (int ct = 0; ct < 8; ++ct) {
      bf16x8 bb = *(const bf16x8*)(kvp + (size_t)((ct * 16 + lr) * 128) + dof);
      acc0[ct] = __builtin_amdgcn_mfma_f32_16x16x32_bf16(a0, bb, acc0[ct], 0, 0, 0);
      acc1[ct] = __builtin_amdgcn_mfma_f32_16x16x32_bf16(a1, bb, acc1[ct], 0, 0, 0);
    }
  }

  float z0[4], z1[4];
#pragma unroll
  for (int j = 0; j < 4; ++j) {
    z0[j] = zrow[w * 32 + lg * 4 + j];
    z1[j] = zrow[w * 32 + 16 + lg * 4 + j];
  }
  float* op = out + qoff;
#pragma unroll
  for (int ct = 0; ct < 8; ++ct)
#pragma unroll
    for (int jj = 0; jj < 4; ++jj) {
      int row = w * 32 + lg * 4 + jj;   // C/D: col=lane&15, row=(lane>>4)*4+jj
      op[(size_t)row * NHD + ct * 16 + lr]        = acc0[ct][jj] * z0[jj];
      op[(size_t)(row + 16) * NHD + ct * 16 + lr] = acc1[ct][jj] * z1[jj];
    }
}

extern "C" void kernel_launch(void* const* d_in, const int* in_sizes, int n_in,
                              void* d_out, int out_size, void* d_ws, size_t ws_size,
                              hipStream_t stream) {
  const float* queries   = (const float*)d_in[0];
  const float* keys      = (const float*)d_in[1];
  const float* values    = (const float*)d_in[2];
  const float* threshold = (const float*)d_in[3];
  float* out = (float*)d_out;

  // ws: kvp CH*2MB | kspart CH*16KB | kvb 1MB | ksumg 16KB   (CH=16 -> ~34.9MB)
  int CH = 16;
  while (CH > 1 &&
         (size_t)CH * (524288 + 32 * 128) * 4 + (size_t)32 * 16384 * 2 + 32 * 128 * 4 > ws_size)
    CH >>= 1;
  float* kvp     = (float*)d_ws;
  float* kspart  = kvp + (size_t)CH * 524288;
  ushort_t* kvb  = (ushort_t*)(kspart + (size_t)CH * 32 * 128);
  float* ksumg   = (float*)(kvb + (size_t)32 * 16384);

  kv_direct<<<dim3(CH, 8, 4), 512, 0, stream>>>(keys, values, kvp, kspart);
  kv_merge<<<dim3(32, 4), 256, 0, stream>>>(kvp, kspart, kvb, ksumg, CH);
  attn_out<<<dim3(64, 32), 256, 0, stream>>>(queries, kvb, ksumg, threshold, out);
}

// Round 9
// 176.040 us; speedup vs baseline: 2.8736x; 1.1014x over previous
//
#include <hip/hip_runtime.h>
#include <stdint.h>

// DynamicSparseLinearAttention on MI355X.
// N=4, L=8192, H=8, D=V=128. Layout [n][l][h][d], row stride H*D = 1024 floats.
//
// Lessons: (R4) atomics write through L2 -> never. (R5) small grids starve the
// chip. (R6) per-lane 16B loads at 4KB stride thrash L2; LDS staging with
// coalesced reads is mandatory. (R8) scalar LDS transpose reads (48 b32/thread
// /step, 4-way conflicts) cap kv_direct at 2.4 TB/s -> stage the tile already
// TRANSPOSED + bf16-PACKED so fragment reads are 6x ds_read_b128.
//
// 3 launches:
//  kv_direct: fused retile+GEMM. Grid (CH=16,8,4)=512 blocks x 512 thr (8 waves
//             = 2d x 4v). Per 32-s step: wave g stages s in [4g,4g+4) (float2
//             loads, full 512B/wave coalescing), packs bf16 s-pairs in VALU,
//             writes LDS [d][s2^swz] (SP=20, b64, ~2-way); fragments = single
//             b128 reads. Private fp32 partials, write-once. Ksum via ones-MFMA.
//  kv_merge:  sum CH partials -> kvb bf16 [nh][v][d] + ksumg.
//  attn_out:  Q staged to LDS bf16 (row*17 padded chunks), score during staging
//             (fp32 + shfl_xor), B-frags direct from L2-hot kvb. One barrier.

#define LSEQ 8192
#define NHD  1024   // H*D
#define SP   20     // LDS dwords per d-row: 16 s-pair slots + 4 pad

typedef __attribute__((ext_vector_type(4))) float f32x4;
typedef __attribute__((ext_vector_type(8))) short bf16x8;
typedef unsigned short ushort_t;

static __device__ __forceinline__ unsigned short f2bf(float x) {
  union { float f; uint32_t u; } v; v.f = x;
  uint32_t r = v.u + 0x7FFFu + ((v.u >> 16) & 1u);  // RNE
  return (unsigned short)(r >> 16);
}
static __device__ __forceinline__ uint32_t pack_bf(float a, float b) {
  return (uint32_t)f2bf(a) | ((uint32_t)f2bf(b) << 16);
}
static __device__ __forceinline__ float featmap(float x) {
  // elu(x)+1 = x+1 (x>0) else exp(x)
  return x > 0.f ? x + 1.f : __expf(x);
}

// ---------------- Phase 1: fused retile + KV GEMM ----------------
// Grid (CH, 8 h, 4 n), 512 thr = 8 waves = 2 wr(d64) x 4 wc(v32).
// LDS: bf16 pairs along s, dword idx = d*SP + (s2 ^ ((d>>2&3)<<2)).
__global__ __launch_bounds__(512) void kv_direct(const float* __restrict__ keys,
                                                 const float* __restrict__ values,
                                                 float* __restrict__ kvp,
                                                 float* __restrict__ kspart) {
  __shared__ uint32_t kls[128 * SP];
  __shared__ uint32_t vls[128 * SP];
  const int tid = threadIdx.x;
  const int chunk = blockIdx.x, CH = gridDim.x;
  const int h = blockIdx.y, n = blockIdx.z, nh = n * 8 + h;
  const int lane = tid & 63, w = tid >> 6;
  const int wr = w >> 2, wc = w & 3;
  const int lr = lane & 15, lg = lane >> 4;
  const int sPer = LSEQ / CH;        // 512 at CH=16
  const int steps = sPer / 32;

  const size_t gb = ((size_t)n * LSEQ + (size_t)chunk * sPer) * NHD + h * 128;
  const float* gk = keys + gb;
  const float* gv = values + gb;

  // staging role: wave w owns s = 4w..4w+3; lane owns d-pair (2*lane, 2*lane+1)
  const int a = lane;
  const int wslot = (2 * w) ^ (((a >> 1) & 3) << 2);   // slot for s2=2w at d=2a,2a+1
  const int wbase0 = (2 * a) * SP + wslot;
  const int wbase1 = (2 * a + 1) * SP + wslot;

  float2 kr[4], vr[4];
#pragma unroll
  for (int j = 0; j < 4; ++j) {
    size_t off = (size_t)(4 * w + j) * NHD + 2 * a;
    kr[j] = *(const float2*)(gk + off);
    vr[j] = *(const float2*)(gv + off);
  }

  f32x4 acc[4][2] = {};
  f32x4 ak[4] = {};
  bf16x8 ones;
  { uint32_t* u = (uint32_t*)&ones; u[0] = u[1] = u[2] = u[3] = 0x3F803F80u; }

  for (int t = 0; t < steps; ++t) {
    // pack (featmap K in fp32, same rounding path as all prior rounds) + write
    {
      uint2 kd0, kd1, vd0, vd1;
      kd0.x = pack_bf(featmap(kr[0].x), featmap(kr[1].x));
      kd0.y = pack_bf(featmap(kr[2].x), featmap(kr[3].x));
      kd1.x = pack_bf(featmap(kr[0].y), featmap(kr[1].y));
      kd1.y = pack_bf(featmap(kr[2].y), featmap(kr[3].y));
      vd0.x = pack_bf(vr[0].x, vr[1].x);
      vd0.y = pack_bf(vr[2].x, vr[3].x);
      vd1.x = pack_bf(vr[0].y, vr[1].y);
      vd1.y = pack_bf(vr[2].y, vr[3].y);
      *(uint2*)&kls[wbase0] = kd0;
      *(uint2*)&kls[wbase1] = kd1;
      *(uint2*)&vls[wbase0] = vd0;
      *(uint2*)&vls[wbase1] = vd1;
    }
    __syncthreads();
    if (t + 1 < steps) {   // issue next step's loads; complete under MFMA
#pragma unroll
      for (int j = 0; j < 4; ++j) {
        size_t off = (size_t)((t + 1) * 32 + 4 * w + j) * NHD + 2 * a;
        kr[j] = *(const float2*)(gk + off);
        vr[j] = *(const float2*)(gv + off);
      }
    }
    // fragment reads: one b128 each, swizzle preserves dword order
    bf16x8 af[4], bfr[2];
#pragma unroll
    for (int fr = 0; fr < 4; ++fr) {
      int d = wr * 64 + fr * 16 + lr;
      af[fr] = *(const bf16x8*)&kls[d * SP + ((4 * lg) ^ ((((d >> 2)) & 3) << 2))];
    }
#pragma unroll
    for (int fc = 0; fc < 2; ++fc) {
      int v = wc * 32 + fc * 16 + lr;
      bfr[fc] = *(const bf16x8*)&vls[v * SP + ((4 * lg) ^ ((((v >> 2)) & 3) << 2))];
    }
#pragma unroll
    for (int fr = 0; fr < 4; ++fr)
#pragma unroll
      for (int fc = 0; fc < 2; ++fc)
        acc[fr][fc] = __builtin_amdgcn_mfma_f32_16x16x32_bf16(af[fr], bfr[fc], acc[fr][fc], 0, 0, 0);
    if (wc == 0) {
#pragma unroll
      for (int fr = 0; fr < 4; ++fr)
        ak[fr] = __builtin_amdgcn_mfma_f32_16x16x32_bf16(af[fr], ones, ak[fr], 0, 0, 0);
    }
    __syncthreads();
  }

  // C/D: col(v)=lane&15, row(d)=(lane>>4)*4+j. Private partial, write-once.
  float* dst = kvp + ((size_t)chunk * 32 + nh) * 16384;
#pragma unroll
  for (int fr = 0; fr < 4; ++fr)
#pragma unroll
    for (int fc = 0; fc < 2; ++fc) {
      int d0 = wr * 64 + fr * 16 + lg * 4;
      int v  = wc * 32 + fc * 16 + lr;
      *(float4*)(dst + (size_t)v * 128 + d0) =
          make_float4(acc[fr][fc][0], acc[fr][fc][1], acc[fr][fc][2], acc[fr][fc][3]);
    }
  if (wc == 0 && lr == 0) {
    float* ks = kspart + ((size_t)chunk * 32 + nh) * 128;
#pragma unroll
    for (int fr = 0; fr < 4; ++fr)
      *(float4*)(ks + wr * 64 + fr * 16 + lg * 4) =
          make_float4(ak[fr][0], ak[fr][1], ak[fr][2], ak[fr][3]);
  }
}

// ---------------- Phase 1c: merge partials ----------------
__global__ __launch_bounds__(256) void kv_merge(const float* __restrict__ kvp,
                                                const float* __restrict__ kspart,
                                                ushort_t* __restrict__ kvb,
                                                float* __restrict__ ksumg,
                                                int CH) {
  const int nh = blockIdx.x, q = blockIdx.y, tid = threadIdx.x;
  const size_t off = (size_t)nh * 16384 + q * 4096;
#pragma unroll
  for (int i = 0; i < 4; ++i) {
    size_t idx = off + (size_t)(i * 256 + tid) * 4;
    f32x4 s = {};
    for (int c = 0; c < CH; ++c)
      s += *(const f32x4*)(kvp + (size_t)c * 524288 + idx);
    *(uint2*)(kvb + idx) = make_uint2(pack_bf(s[0], s[1]), pack_bf(s[2], s[3]));
  }
  if (q == 0 && tid < 128) {
    float s = 0.f;
    for (int c = 0; c < CH; ++c) s += kspart[((size_t)c * 32 + nh) * 128 + tid];
    ksumg[nh * 128 + tid] = s;
  }
}

// ---------------- Phase 2: LDS-staged Q + direct-global B ----------------
__global__ __launch_bounds__(256, 4) void attn_out(const float* __restrict__ q,
                                                   const ushort_t* __restrict__ kvb,
                                                   const float* __restrict__ ksumg,
                                                   const float* __restrict__ thrp,
                                                   float* __restrict__ out) {
  __shared__ __align__(16) uint32_t As[128 * 17 * 4];  // 34.8KB
  __shared__ float zrow[128];

  const int tid = threadIdx.x;
  const int mc = blockIdx.x, nh = blockIdx.y;
  const int n = nh >> 3, h = nh & 7;
  const size_t qoff = ((size_t)(n * LSEQ + mc * 128)) * NHD + h * 128;
  const float thr = thrp[0];

  const int c4 = tid & 31;
  const float4 kk = *(const float4*)(ksumg + nh * 128 + c4 * 4);

  // ---- stage Qf -> As (bf16) + fp32 score on the fly ----
#pragma unroll
  for (int it = 0; it < 16; ++it) {
    int rr = it * 8 + (tid >> 5);
    float4 qv = *(const float4*)(q + qoff + (size_t)rr * NHD + c4 * 4);
    float f0 = featmap(qv.x), f1 = featmap(qv.y), f2 = featmap(qv.z), f3 = featmap(qv.w);
    uint32_t* dst = &As[(rr * 17 + (c4 >> 1)) * 4 + (c4 & 1) * 2];
    dst[0] = pack_bf(f0, f1);
    dst[1] = pack_bf(f2, f3);
    float p = f0 * kk.x + f1 * kk.y + f2 * kk.z + f3 * kk.w;
    p += __shfl_xor(p, 1);  p += __shfl_xor(p, 2);  p += __shfl_xor(p, 4);
    p += __shfl_xor(p, 8);  p += __shfl_xor(p, 16);
    if (c4 == 0) {
      float sp = p > thr ? p : 0.f;
      zrow[rr] = 1.f / (sp + 1e-6f);
    }
  }
  __syncthreads();

  // ---- MFMA: A from LDS, B direct from kvb (L2-hot 32KB) ----
  const int lane = tid & 63;
  const int w = tid >> 6;
  const int lr = lane & 15, lg = lane >> 4;
  const ushort_t* kvp = kvb + (size_t)nh * 16384;   // [v][d] bf16

  f32x4 acc0[8] = {};
  f32x4 acc1[8] = {};
#pragma unroll
  for (int ks = 0; ks < 4; ++ks) {
    const int c8 = ks * 4 + lg;
    const int dof = ks * 32 + lg * 8;
    const int r0 = w * 32 + lr;
    bf16x8 a0 = *(const bf16x8*)&As[(r0 * 17 + c8) * 4];
    bf16x8 a1 = *(const bf16x8*)&As[((r0 + 16) * 17 + c8) * 4];
#pragma unroll
    for (int ct = 0; ct < 8; ++ct) {
      bf16x8 bb = *(const bf16x8*)(kvp + (size_t)((ct * 16 + lr) * 128) + dof);
      acc0[ct] = __builtin_amdgcn_mfma_f32_16x16x32_bf16(a0, bb, acc0[ct], 0, 0, 0);
      acc1[ct] = __builtin_amdgcn_mfma_f32_16x16x32_bf16(a1, bb, acc1[ct], 0, 0, 0);
    }
  }

  float z0[4], z1[4];
#pragma unroll
  for (int j = 0; j < 4; ++j) {
    z0[j] = zrow[w * 32 + lg * 4 + j];
    z1[j] = zrow[w * 32 + 16 + lg * 4 + j];
  }
  float* op = out + qoff;
#pragma unroll
  for (int ct = 0; ct < 8; ++ct)
#pragma unroll
    for (int jj = 0; jj < 4; ++jj) {
      int row = w * 32 + lg * 4 + jj;   // C/D: col=lane&15, row=(lane>>4)*4+jj
      op[(size_t)row * NHD + ct * 16 + lr]        = acc0[ct][jj] * z0[jj];
      op[(size_t)(row + 16) * NHD + ct * 16 + lr] = acc1[ct][jj] * z1[jj];
    }
}

extern "C" void kernel_launch(void* const* d_in, const int* in_sizes, int n_in,
                              void* d_out, int out_size, void* d_ws, size_t ws_size,
                              hipStream_t stream) {
  const float* queries   = (const float*)d_in[0];
  const float* keys      = (const float*)d_in[1];
  const float* values    = (const float*)d_in[2];
  const float* threshold = (const float*)d_in[3];
  float* out = (float*)d_out;

  // ws: kvp CH*2MB | kspart CH*16KB | kvb 1MB | ksumg 16KB   (CH=16 -> ~34.9MB)
  int CH = 16;
  while (CH > 1 &&
         (size_t)CH * (524288 + 32 * 128) * 4 + (size_t)32 * 16384 * 2 + 32 * 128 * 4 > ws_size)
    CH >>= 1;
  float* kvp     = (float*)d_ws;
  float* kspart  = kvp + (size_t)CH * 524288;
  ushort_t* kvb  = (ushort_t*)(kspart + (size_t)CH * 32 * 128);
  float* ksumg   = (float*)(kvb + (size_t)32 * 16384);

  kv_direct<<<dim3(CH, 8, 4), 512, 0, stream>>>(keys, values, kvp, kspart);
  kv_merge<<<dim3(32, 4), 256, 0, stream>>>(kvp, kspart, kvb, ksumg, CH);
  attn_out<<<dim3(64, 32), 256, 0, stream>>>(queries, kvb, ksumg, threshold, out);
}

// Round 10
// 172.487 us; speedup vs baseline: 2.9328x; 1.0206x over previous
//
#include <hip/hip_runtime.h>
#include <stdint.h>

// DynamicSparseLinearAttention on MI355X.
// N=4, L=8192, H=8, D=V=128. Layout [n][l][h][d], row stride H*D = 1024 floats.
//
// Lessons: (R4) atomics write through L2 -> never. (R5) small grids starve the
// chip. (R6) per-lane 16B loads at 4KB stride thrash L2; LDS staging with
// coalesced reads is mandatory. (R8) scalar LDS transpose reads cap at 2.4TB/s
// -> stage transposed+bf16-packed, frag reads = ds_read_b128. (R9) 1-step
// prefetch leaves a ~650cy vmcnt stall per step (HBM latency ~900cy vs ~250cy
// of per-step work) -> 2-step register prefetch + double-buffered LDS with ONE
// barrier per step.
//
// 3 launches:
//  kv_direct: fused retile+GEMM. Grid (CH=16,8,4)=512 blocks x 512 thr (8 waves
//             = 2d x 4v). Pipeline: regs P/Q hold steps t+2/t+3 in flight; LDS
//             buffers A/B alternate; one barrier per step. LDS [d][s2^f(d)],
//             SP=20, f(d)=4*((d>>3)&3) -> b64 writes ~8 bank-pairs, b128 reads
//             2-way (free). Private fp32 partials, write-once. Ksum via
//             ones-MFMA on wc==0 waves.
//  kv_merge:  sum CH partials -> kvb bf16 [nh][v][d] + ksumg.
//  attn_out:  Q staged to LDS bf16 (row*17 padded chunks), score during staging
//             (fp32 + shfl_xor), B-frags direct from L2-hot kvb. One barrier.

#define LSEQ 8192
#define NHD  1024   // H*D
#define SP   20     // LDS dwords per d-row: 16 s-pair slots + 4 pad

typedef __attribute__((ext_vector_type(4))) float f32x4;
typedef __attribute__((ext_vector_type(8))) short bf16x8;
typedef unsigned short ushort_t;

static __device__ __forceinline__ unsigned short f2bf(float x) {
  union { float f; uint32_t u; } v; v.f = x;
  uint32_t r = v.u + 0x7FFFu + ((v.u >> 16) & 1u);  // RNE
  return (unsigned short)(r >> 16);
}
static __device__ __forceinline__ uint32_t pack_bf(float a, float b) {
  return (uint32_t)f2bf(a) | ((uint32_t)f2bf(b) << 16);
}
static __device__ __forceinline__ float featmap(float x) {
  // elu(x)+1 = x+1 (x>0) else exp(x)
  return x > 0.f ? x + 1.f : __expf(x);
}

// ---------------- Phase 1: fused retile + KV GEMM, 2-deep pipeline ----------
// Grid (CH, 8 h, 4 n), 512 thr = 8 waves = 2 wr(d64) x 4 wc(v32).
__global__ __launch_bounds__(512, 4) void kv_direct(const float* __restrict__ keys,
                                                    const float* __restrict__ values,
                                                    float* __restrict__ kvp,
                                                    float* __restrict__ kspart) {
  __shared__ uint32_t klsA[128 * SP];
  __shared__ uint32_t vlsA[128 * SP];
  __shared__ uint32_t klsB[128 * SP];
  __shared__ uint32_t vlsB[128 * SP];
  const int tid = threadIdx.x;
  const int chunk = blockIdx.x, CH = gridDim.x;
  const int h = blockIdx.y, n = blockIdx.z, nh = n * 8 + h;
  const int lane = tid & 63, w = tid >> 6;
  const int wr = w >> 2, wc = w & 3;
  const int lr = lane & 15, lg = lane >> 4;
  const int sPer = LSEQ / CH;        // 512 at CH=16
  const int steps = sPer / 32;       // 16 at CH=16 (always even)

  const size_t gb = ((size_t)n * LSEQ + (size_t)chunk * sPer) * NHD + h * 128;
  const float* gk = keys + gb;
  const float* gv = values + gb;

  // staging role: wave w owns s = 4w..4w+3; lane owns d-pair (2*lane, 2*lane+1)
  const int a = lane;
  const int fsw = 4 * ((a >> 2) & 3);          // = 4*((d>>3)&3) for d=2a,2a+1
  const int wslot = (2 * w) ^ fsw;
  const int wbase0 = (2 * a) * SP + wslot;
  const int wbase1 = (2 * a + 1) * SP + wslot;

  f32x4 acc[4][2] = {};
  f32x4 ak[4] = {};
  bf16x8 ones;
  { uint32_t* u = (uint32_t*)&ones; u[0] = u[1] = u[2] = u[3] = 0x3F803F80u; }

#define ISSUE(KR, VR, T)                                        \
  do {                                                          \
    _Pragma("unroll") for (int j = 0; j < 4; ++j) {             \
      size_t off = (size_t)((T) * 32 + 4 * w + j) * NHD + 2 * a;\
      KR[j] = *(const float2*)(gk + off);                       \
      VR[j] = *(const float2*)(gv + off);                       \
    }                                                           \
  } while (0)

#define STAGE(KLS, VLS, KR, VR)                                 \
  do {                                                          \
    uint2 kd0, kd1, vd0, vd1;                                   \
    kd0.x = pack_bf(featmap(KR[0].x), featmap(KR[1].x));        \
    kd0.y = pack_bf(featmap(KR[2].x), featmap(KR[3].x));        \
    kd1.x = pack_bf(featmap(KR[0].y), featmap(KR[1].y));        \
    kd1.y = pack_bf(featmap(KR[2].y), featmap(KR[3].y));        \
    vd0.x = pack_bf(VR[0].x, VR[1].x);                          \
    vd0.y = pack_bf(VR[2].x, VR[3].x);                          \
    vd1.x = pack_bf(VR[0].y, VR[1].y);                          \
    vd1.y = pack_bf(VR[2].y, VR[3].y);                          \
    *(uint2*)&KLS[wbase0] = kd0;                                \
    *(uint2*)&KLS[wbase1] = kd1;                                \
    *(uint2*)&VLS[wbase0] = vd0;                                \
    *(uint2*)&VLS[wbase1] = vd1;                                \
  } while (0)

#define FRAGS_MFMA(KLS, VLS)                                                       \
  do {                                                                             \
    bf16x8 af[4], bfr[2];                                                          \
    _Pragma("unroll") for (int fr = 0; fr < 4; ++fr) {                             \
      int d = wr * 64 + fr * 16 + lr;                                              \
      af[fr] = *(const bf16x8*)&KLS[d * SP + ((4 * lg) ^ (4 * ((d >> 3) & 3)))];   \
    }                                                                              \
    _Pragma("unroll") for (int fc = 0; fc < 2; ++fc) {                             \
      int v = wc * 32 + fc * 16 + lr;                                              \
      bfr[fc] = *(const bf16x8*)&VLS[v * SP + ((4 * lg) ^ (4 * ((v >> 3) & 3)))];  \
    }                                                                              \
    _Pragma("unroll") for (int fr = 0; fr < 4; ++fr)                               \
      _Pragma("unroll") for (int fc = 0; fc < 2; ++fc)                             \
        acc[fr][fc] =                                                              \
            __builtin_amdgcn_mfma_f32_16x16x32_bf16(af[fr], bfr[fc], acc[fr][fc], 0, 0, 0); \
    if (wc == 0) {                                                                 \
      _Pragma("unroll") for (int fr = 0; fr < 4; ++fr)                             \
        ak[fr] = __builtin_amdgcn_mfma_f32_16x16x32_bf16(af[fr], ones, ak[fr], 0, 0, 0); \
    }                                                                              \
  } while (0)

  float2 krP[4], vrP[4], krQ[4], vrQ[4];
  ISSUE(krP, vrP, 0);
  ISSUE(krQ, vrQ, 1);

  for (int t = 0; t < steps; t += 2) {
    // even substep: P -> A
    STAGE(klsA, vlsA, krP, vrP);
    __syncthreads();
    if (t + 2 < steps) ISSUE(krP, vrP, t + 2);
    FRAGS_MFMA(klsA, vlsA);
    // odd substep: Q -> B
    STAGE(klsB, vlsB, krQ, vrQ);
    __syncthreads();
    if (t + 3 < steps) ISSUE(krQ, vrQ, t + 3);
    FRAGS_MFMA(klsB, vlsB);
  }
#undef ISSUE
#undef STAGE
#undef FRAGS_MFMA

  // C/D: col(v)=lane&15, row(d)=(lane>>4)*4+j. Private partial, write-once.
  float* dst = kvp + ((size_t)chunk * 32 + nh) * 16384;
#pragma unroll
  for (int fr = 0; fr < 4; ++fr)
#pragma unroll
    for (int fc = 0; fc < 2; ++fc) {
      int d0 = wr * 64 + fr * 16 + lg * 4;
      int v  = wc * 32 + fc * 16 + lr;
      *(float4*)(dst + (size_t)v * 128 + d0) =
          make_float4(acc[fr][fc][0], acc[fr][fc][1], acc[fr][fc][2], acc[fr][fc][3]);
    }
  if (wc == 0 && lr == 0) {
    float* ks = kspart + ((size_t)chunk * 32 + nh) * 128;
#pragma unroll
    for (int fr = 0; fr < 4; ++fr)
      *(float4*)(ks + wr * 64 + fr * 16 + lg * 4) =
          make_float4(ak[fr][0], ak[fr][1], ak[fr][2], ak[fr][3]);
  }
}

// ---------------- Phase 1c: merge partials ----------------
__global__ __launch_bounds__(256) void kv_merge(const float* __restrict__ kvp,
                                                const float* __restrict__ kspart,
                                                ushort_t* __restrict__ kvb,
                                                float* __restrict__ ksumg,
                                                int CH) {
  const int nh = blockIdx.x, q = blockIdx.y, tid = threadIdx.x;
  const size_t off = (size_t)nh * 16384 + q * 4096;
#pragma unroll
  for (int i = 0; i < 4; ++i) {
    size_t idx = off + (size_t)(i * 256 + tid) * 4;
    f32x4 s = {};
    for (int c = 0; c < CH; ++c)
      s += *(const f32x4*)(kvp + (size_t)c * 524288 + idx);
    *(uint2*)(kvb + idx) = make_uint2(pack_bf(s[0], s[1]), pack_bf(s[2], s[3]));
  }
  if (q == 0 && tid < 128) {
    float s = 0.f;
    for (int c = 0; c < CH; ++c) s += kspart[((size_t)c * 32 + nh) * 128 + tid];
    ksumg[nh * 128 + tid] = s;
  }
}

// ---------------- Phase 2: LDS-staged Q + direct-global B ----------------
__global__ __launch_bounds__(256, 4) void attn_out(const float* __restrict__ q,
                                                   const ushort_t* __restrict__ kvb,
                                                   const float* __restrict__ ksumg,
                                                   const float* __restrict__ thrp,
                                                   float* __restrict__ out) {
  __shared__ __align__(16) uint32_t As[128 * 17 * 4];  // 34.8KB
  __shared__ float zrow[128];

  const int tid = threadIdx.x;
  const int mc = blockIdx.x, nh = blockIdx.y;
  const int n = nh >> 3, h = nh & 7;
  const size_t qoff = ((size_t)(n * LSEQ + mc * 128)) * NHD + h * 128;
  const float thr = thrp[0];

  const int c4 = tid & 31;
  const float4 kk = *(const float4*)(ksumg + nh * 128 + c4 * 4);

  // ---- stage Qf -> As (bf16) + fp32 score on the fly ----
#pragma unroll
  for (int it = 0; it < 16; ++it) {
    int rr = it * 8 + (tid >> 5);
    float4 qv = *(const float4*)(q + qoff + (size_t)rr * NHD + c4 * 4);
    float f0 = featmap(qv.x), f1 = featmap(qv.y), f2 = featmap(qv.z), f3 = featmap(qv.w);
    uint32_t* dst = &As[(rr * 17 + (c4 >> 1)) * 4 + (c4 & 1) * 2];
    dst[0] = pack_bf(f0, f1);
    dst[1] = pack_bf(f2, f3);
    float p = f0 * kk.x + f1 * kk.y + f2 * kk.z + f3 * kk.w;
    p += __shfl_xor(p, 1);  p += __shfl_xor(p, 2);  p += __shfl_xor(p, 4);
    p += __shfl_xor(p, 8);  p += __shfl_xor(p, 16);
    if (c4 == 0) {
      float sp = p > thr ? p : 0.f;
      zrow[rr] = 1.f / (sp + 1e-6f);
    }
  }
  __syncthreads();

  // ---- MFMA: A from LDS, B direct from kvb (L2-hot 32KB) ----
  const int lane = tid & 63;
  const int w = tid >> 6;
  const int lr = lane & 15, lg = lane >> 4;
  const ushort_t* kvp = kvb + (size_t)nh * 16384;   // [v][d] bf16

  f32x4 acc0[8] = {};
  f32x4 acc1[8] = {};
#pragma unroll
  for (int ks = 0; ks < 4; ++ks) {
    const int c8 = ks * 4 + lg;
    const int dof = ks * 32 + lg * 8;
    const int r0 = w * 32 + lr;
    bf16x8 a0 = *(const bf16x8*)&As[(r0 * 17 + c8) * 4];
    bf16x8 a1 = *(const bf16x8*)&As[((r0 + 16) * 17 + c8) * 4];
#pragma unroll
    for (int ct = 0; ct < 8; ++ct) {
      bf16x8 bb = *(const bf16x8*)(kvp + (size_t)((ct * 16 + lr) * 128) + dof);
      acc0[ct] = __builtin_amdgcn_mfma_f32_16x16x32_bf16(a0, bb, acc0[ct], 0, 0, 0);
      acc1[ct] = __builtin_amdgcn_mfma_f32_16x16x32_bf16(a1, bb, acc1[ct], 0, 0, 0);
    }
  }

  float z0[4], z1[4];
#pragma unroll
  for (int j = 0; j < 4; ++j) {
    z0[j] = zrow[w * 32 + lg * 4 + j];
    z1[j] = zrow[w * 32 + 16 + lg * 4 + j];
  }
  float* op = out + qoff;
#pragma unroll
  for (int ct = 0; ct < 8; ++ct)
#pragma unroll
    for (int jj = 0; jj < 4; ++jj) {
      int row = w * 32 + lg * 4 + jj;   // C/D: col=lane&15, row=(lane>>4)*4+jj
      op[(size_t)row * NHD + ct * 16 + lr]        = acc0[ct][jj] * z0[jj];
      op[(size_t)(row + 16) * NHD + ct * 16 + lr] = acc1[ct][jj] * z1[jj];
    }
}

extern "C" void kernel_launch(void* const* d_in, const int* in_sizes, int n_in,
                              void* d_out, int out_size, void* d_ws, size_t ws_size,
                              hipStream_t stream) {
  const float* queries   = (const float*)d_in[0];
  const float* keys      = (const float*)d_in[1];
  const float* values    = (const float*)d_in[2];
  const float* threshold = (const float*)d_in[3];
  float* out = (float*)d_out;

  // ws: kvp CH*2MB | kspart CH*16KB | kvb 1MB | ksumg 16KB   (CH=16 -> ~34.9MB)
  int CH = 16;
  while (CH > 1 &&
         (size_t)CH * (524288 + 32 * 128) * 4 + (size_t)32 * 16384 * 2 + 32 * 128 * 4 > ws_size)
    CH >>= 1;
  float* kvp     = (float*)d_ws;
  float* kspart  = kvp + (size_t)CH * 524288;
  ushort_t* kvb  = (ushort_t*)(kspart + (size_t)CH * 32 * 128);
  float* ksumg   = (float*)(kvb + (size_t)32 * 16384);

  kv_direct<<<dim3(CH, 8, 4), 512, 0, stream>>>(keys, values, kvp, kspart);
  kv_merge<<<dim3(32, 4), 256, 0, stream>>>(kvp, kspart, kvb, ksumg, CH);
  attn_out<<<dim3(64, 32), 256, 0, stream>>>(queries, kvb, ksumg, threshold, out);
}